// Round 16
// baseline (1117.897 us; speedup 1.0000x reference)
//
#include <hip/hip_runtime.h>
#include <hip/hip_bf16.h>

using bf16 = __hip_bfloat16;
typedef __attribute__((ext_vector_type(4))) float f32x4;
typedef __attribute__((ext_vector_type(8))) short s16x8;

#define DEV static __device__ __forceinline__
DEV float bf2f(bf16 x){ return __bfloat162float(x); }
DEV bf16  f2bf(float x){ return __float2bfloat16(x); }
DEV float silu_(float x){ return x / (1.f + expf(-x)); }
// 16B-block XOR swizzle inside a 128x64 bf16 tile (row stride 64 elems = 8 blocks)
DEV int swz(int row, int colEl){ return row*64 + ((((colEl) >> 3) ^ (row & 7)) << 3); }

// ------------------------------------------------------------------
// Pipelined bf16 MFMA GEMM core:  C = alpha * (A @ B^T) (+ bias)
// A bf16. ABLK: A stored kblk-major [k/64][Mtot(=lda)][64] (h1 layout).
// B f32 or bf16. bidx = z>>bshift picks {B0*,B1*}; PAIRB: B row r ->
// (r&1 ? upper : lower)[r>>1]; else row >= nsplitB uses upper at
// row-nsplitB. e = z & mask strides by b_zoff. EXPERT: Meff=counts[z],
// rowbase=offsets[z]; GATHER via rowlist. OUT: 0=f32, 1=bf16,
// 3=pair-epilogue silu(even)*odd -> bf16 into kblk-major [n0/128][ldc=Mtot][64].
// MT2: block handles two consecutive m-tiles (B panel reused via L2).
// LDS: unpadded 128x64 tiles with XOR-16B swizzle (32 KB -> 5 blocks/CU).
// ksplit: z=zz/ksplit, split writes +split*c_spo.
// ------------------------------------------------------------------
template<bool B_F32, bool EXPERT, bool GATHER, int OUT, bool BIAS, bool PAIRB, bool ABLK, bool MT2>
DEV void gemm_core(
    const bf16* __restrict__ A,
    const void* __restrict__ B0a, const void* __restrict__ B0b,
    const void* __restrict__ B1a, const void* __restrict__ B1b,
    const float* __restrict__ bias, void* __restrict__ C,
    int M, int N, int K, int lda,
    long a_zoff, long b_zoff, int bshift, int biasz, int nsplitB,
    int zdiv, long c_so, long c_si, int ldc,
    float alpha, int ksplit, long c_spo,
    const int* __restrict__ rowlist, const int* __restrict__ offsets,
    const int* __restrict__ counts)
{
  __shared__ __align__(16) char smem_[32768];
  bf16* As = (bf16*)smem_;
  bf16* Bs = (bf16*)(smem_ + 16384);
  float (*st)[132] = (float(*)[132])smem_;

  const int zz = blockIdx.z;
  const int n0 = blockIdx.x * 128;
  const int z = zz / ksplit, split = zz % ksplit;
  int Meff = M; long rowbase = 0;
  if (EXPERT){ Meff = counts[z]; rowbase = offsets[z]; }
  int m0 = blockIdx.y * (MT2 ? 256 : 128);
  if (m0 >= Meff) return;
  int mend = m0 + (MT2 ? 256 : 128);
  if (mend > Meff) mend = ((Meff + 127) & ~127);  // partial last tile handled by masks
  const bf16* Ab = A + (EXPERT ? 0 : z * a_zoff);
  const int bidx = z >> bshift;
  const long e = (long)(z & ((1 << bshift) - 1));
  const void* BL = bidx ? B1a : B0a;
  const void* BU = bidx ? B1b : B0b;
  long coff;
  if (EXPERT) coff = rowbase * (long)ldc;
  else        coff = (long)(z / zdiv) * c_so + (long)(z % zdiv) * c_si;
  coff += (long)split * c_spo;
  const float* bias_eff = BIAS ? bias + (long)bidx * biasz : nullptr;

  const int klen = K / ksplit;
  const int kbeg = split * klen;
  const int NT = klen >> 6;

  const int tid = threadIdx.x;
  const int lane = tid & 63, wid = tid >> 6;
  const int wm = wid >> 1, wn = wid & 1;
  const int rbase = tid >> 3;
  const int kc = (tid & 7) << 3;

  // ---- B pointers (once per block; reused across m-tiles) ----
  const bf16* bp[4]; const float* bpf[4];
  bool bvalid[4];
  #pragma unroll
  for (int it = 0; it < 4; it++){
    int br = n0 + rbase + 32 * it;
    bvalid[it] = br < N;
    int brc = bvalid[it] ? br : 0;
    const void* Bsel; long brr;
    if (PAIRB){ Bsel = (brc & 1) ? BU : BL; brr = brc >> 1; }
    else { bool up = brc >= nsplitB; Bsel = up ? BU : BL; brr = up ? (brc - nsplitB) : brc; }
    if (B_F32) bpf[it] = (const float*)Bsel + e * b_zoff + brr * K + kbeg + kc;
    else       bp[it]  = (const bf16*) Bsel + e * b_zoff + brr * K + kbeg + kc;
  }

  const uint4 zero4 = make_uint4(0u,0u,0u,0u);
  const int er = tid >> 3;
  const int ec = (tid & 7) << 4;
  f32x4 acc[4][4];

  do {
    // ---- A pointers for this m-tile ----
    const bf16* ap[4];
    bool avalid[4];
    #pragma unroll
    for (int it = 0; it < 4; it++){
      int row = rbase + 32 * it;
      long ar = 0;
      if (EXPERT){
        int i = m0 + row;
        avalid[it] = i < Meff;
        if (avalid[it]) ar = GATHER ? (long)rowlist[rowbase + i] : (rowbase + i);
      } else {
        avalid[it] = (m0 + row) < Meff;
        ar = m0 + row;
      }
      if (ABLK) ap[it] = Ab + ((long)(kbeg >> 6) * lda + ar) * 64 + kc;
      else      ap[it] = Ab + ar * (long)lda + kbeg + kc;
    }

    #pragma unroll
    for (int mi = 0; mi < 4; mi++)
      #pragma unroll
      for (int ni = 0; ni < 4; ni++)
        acc[mi][ni] = f32x4{0.f,0.f,0.f,0.f};

    uint4 ra[4], rb[4];
    float4 fb0[4], fb1[4];
    auto LOAD = [&](int koff){
      long aoff = ABLK ? (long)koff * lda : (long)koff;
      #pragma unroll
      for (int it = 0; it < 4; it++){
        ra[it] = avalid[it] ? *(const uint4*)(ap[it] + aoff) : zero4;
        if (B_F32){
          if (bvalid[it]){ fb0[it] = *(const float4*)(bpf[it] + koff);
                           fb1[it] = *(const float4*)(bpf[it] + koff + 4); }
          else { fb0[it] = make_float4(0,0,0,0); fb1[it] = make_float4(0,0,0,0); }
        } else {
          rb[it] = bvalid[it] ? *(const uint4*)(bp[it] + koff) : zero4;
        }
      }
    };
    auto STORE = [&](){
      #pragma unroll
      for (int it = 0; it < 4; it++){
        int row = rbase + 32 * it;
        *(uint4*)(As + swz(row, kc)) = ra[it];
        if (B_F32){
          union { bf16 h[8]; uint4 v; } u;
          u.h[0]=f2bf(fb0[it].x); u.h[1]=f2bf(fb0[it].y); u.h[2]=f2bf(fb0[it].z); u.h[3]=f2bf(fb0[it].w);
          u.h[4]=f2bf(fb1[it].x); u.h[5]=f2bf(fb1[it].y); u.h[6]=f2bf(fb1[it].z); u.h[7]=f2bf(fb1[it].w);
          *(uint4*)(Bs + swz(row, kc)) = u.v;
        } else {
          *(uint4*)(Bs + swz(row, kc)) = rb[it];
        }
      }
    };

    LOAD(0);
    for (int t = 0; t < NT; t++){
      STORE();
      __syncthreads();
      if (t + 1 < NT) LOAD((t + 1) << 6);
      #pragma unroll
      for (int ks2 = 0; ks2 < 2; ks2++){
        const int r16 = lane & 15;
        const int kk = ks2 * 32 + ((lane >> 4) << 3);
        s16x8 af[4], bfr[4];
        #pragma unroll
        for (int mi = 0; mi < 4; mi++) af[mi]  = *(const s16x8*)(As + swz(wm*64 + mi*16 + r16, kk));
        #pragma unroll
        for (int ni = 0; ni < 4; ni++) bfr[ni] = *(const s16x8*)(Bs + swz(wn*64 + ni*16 + r16, kk));
        #pragma unroll
        for (int mi = 0; mi < 4; mi++)
          #pragma unroll
          for (int ni = 0; ni < 4; ni++)
            acc[mi][ni] = __builtin_amdgcn_mfma_f32_16x16x32_bf16(af[mi], bfr[ni], acc[mi][ni], 0, 0, 0);
      }
      __syncthreads();
    }

    // ---- LDS-staged coalesced epilogue ----
    const int erg = m0 + (er & 15) + ((er & 16) ? 64 : 0);
    #pragma unroll
    for (int mi = 0; mi < 4; mi++){
      #pragma unroll
      for (int ni = 0; ni < 4; ni++){
        int lc = wn*64 + ni*16 + (lane & 15);
        float bv = 0.f;
        if (BIAS){ if (split == 0) bv = bias_eff[n0 + lc]; }
        #pragma unroll
        for (int i = 0; i < 4; i++){
          int lr = wm*16 + ((lane >> 4) << 2) + i;
          st[lr][lc] = acc[mi][ni][i] * alpha + bv;
        }
      }
      __syncthreads();
      int rg = erg + mi*16;
      if (rg < Meff){
        if (OUT == 3){
          long base = ((long)(n0 >> 7) * (long)ldc + rowbase + rg) * 64 + (ec >> 1);
          union { bf16 h[8]; uint4 v; } o;
          #pragma unroll
          for (int j = 0; j < 8; j++)
            o.h[j] = f2bf(silu_(st[er][ec + 2*j]) * st[er][ec + 2*j + 1]);
          *(uint4*)((bf16*)C + base) = o.v;
        } else {
          int cg = n0 + ec;
          if (cg < N){
            long base = coff + (long)rg * ldc + cg;
            if (OUT == 0){
              float* dst = (float*)C + base;
              #pragma unroll
              for (int q = 0; q < 4; q++)
                *(float4*)(dst + 4*q) = make_float4(st[er][ec+4*q], st[er][ec+4*q+1],
                                                    st[er][ec+4*q+2], st[er][ec+4*q+3]);
            } else {
              union { bf16 h[8]; uint4 v; } o0, o1;
              #pragma unroll
              for (int j = 0; j < 8; j++){
                o0.h[j] = f2bf(st[er][ec+j]);
                o1.h[j] = f2bf(st[er][ec+8+j]);
              }
              *(uint4*)((bf16*)C + base)     = o0.v;
              *(uint4*)((bf16*)C + base + 8) = o1.v;
            }
          }
        }
      }
      __syncthreads();
    }
    m0 += 128;
  } while (MT2 && m0 < mend && m0 < Meff);
}

#define GEMM_K(NAME, BF32, EXPERT, GATHER, OUT, BIAS, PAIRB, ABLK, MT2)            \
__global__ __launch_bounds__(256) void NAME(                                       \
    const bf16* A, const void* B0a, const void* B0b, const void* B1a,              \
    const void* B1b, const float* bias, void* C,                                   \
    int M, int N, int K, int lda, long az, long bz, int bshift, int biasz,         \
    int nsplitB, int zdiv, long cso, long csi, int ldc, float alpha, int ks,       \
    long cspo, const int* rl, const int* ofs, const int* cnt){                     \
  gemm_core<BF32,EXPERT,GATHER,OUT,BIAS,PAIRB,ABLK,MT2>(A,B0a,B0b,B1a,B1b,bias,C,  \
      M,N,K,lda,az,bz,bshift,biasz,nsplitB,zdiv,cso,csi,ldc,alpha,ks,cspo,rl,ofs,cnt); }

GEMM_K(k_qkv,  true ,true ,false,1,true ,false,false,false)
GEMM_K(k_qkt,  false,false,false,1,false,false,false,false)
GEMM_K(k_pv,   false,false,false,0,false,false,false,false)
GEMM_K(k_proj, true ,true ,false,0,true ,false,false,false)
GEMM_K(k_gup,  true ,true ,true ,3,false,true ,false,true )
GEMM_K(k_down, true ,true ,false,1,false,false,true ,true )
GEMM_K(k_sgup, true ,true ,false,3,false,true ,false,false)
GEMM_K(k_sdown,true ,true ,false,0,false,false,true ,false)

// ---- init / tables ----
__global__ void init_kernel(int* cnt16, int* tabs){
  int i = threadIdx.x;
  if (i < 16) cnt16[i] = 0;
  if (i == 0){
    tabs[0]=2048; tabs[1]=512; tabs[2]=0; tabs[3]=2048;          // qkv cnt/ofs
    tabs[4]=256; tabs[5]=256; tabs[6]=1024; tabs[7]=1024;        // proj cnt
    tabs[8]=0; tabs[9]=1280; tabs[10]=256; tabs[11]=1536;        // proj ofs
    tabs[12]=2048; tabs[13]=512; tabs[14]=0; tabs[15]=2048;      // shared cnt/ofs
  }
}
__global__ void tables_kernel(const int* cnt16, int* ofs16, int* cur16){
  if (threadIdx.x == 0){
    int o = 0;
    for (int e = 0; e < 8; e++){ ofs16[e] = o; o += cnt16[e]; cur16[e] = 0; }
    o = 4096;
    for (int e = 8; e < 16; e++){ ofs16[e] = o; o += cnt16[e]; cur16[e] = 0; }
  }
}

// ---- O partial reduce: Opart[5][NH][1280][64] f32 -> O bf16 ----
__global__ __launch_bounds__(256) void reduce_o_kernel(const float* __restrict__ Op,
    bf16* __restrict__ O, int nh){
  int bh = blockIdx.y;
  int b = bh / 12, hh = bh % 12;
  int d = threadIdx.x & 63, rr = threadIdx.x >> 6;
  const float* base = Op + (long)bh * 1280 * 64;
  #pragma unroll
  for (int j = 0; j < 4; j++){
    int row = blockIdx.x * 16 + rr * 4 + j;
    float s = 0.f;
    #pragma unroll
    for (int sp = 0; sp < 5; sp++) s += base[(long)sp*nh*1280*64 + (long)row*64 + d];
    O[((long)b*1280 + row)*768 + hh*64 + d] = f2bf(s);
  }
}

// ---- modulation GEMV ----
__global__ __launch_bounds__(256) void mod_kernel(const float* __restrict__ vec,
    const float* __restrict__ w, const float* __restrict__ b, float* __restrict__ out){
  int bb = blockIdx.y;
  __shared__ float sv[768];
  int tid = threadIdx.x;
  for (int i = tid; i < 768; i += 256){ float v = vec[bb*768 + i]; sv[i] = v/(1.f+expf(-v)); }
  __syncthreads();
  int w4 = tid >> 6, lane = tid & 63;
  int j0 = blockIdx.x * 8 + w4 * 2;
  for (int jj = 0; jj < 2; jj++){
    int j = j0 + jj;
    const float* wr = w + (long)j * 768;
    float p = 0.f;
    #pragma unroll
    for (int i = 0; i < 12; i++) p += sv[lane + 64*i] * wr[lane + 64*i];
    for (int o = 32; o; o >>= 1) p += __shfl_xor(p, o);
    if (lane == 0) out[bb*4608 + j] = p + b[j];
  }
}

// ---- y = (1+c)*LN(x) + s ----
__global__ __launch_bounds__(256) void ln_mod_kernel(const float* __restrict__ x,
    const float* __restrict__ mod, bf16* __restrict__ y, int L){
  int t = blockIdx.x; int b = t / L;
  const float* xr = x + (long)t * 768;
  __shared__ float red[256];
  int tid = threadIdx.x;
  float v[3]; float s = 0.f;
  #pragma unroll
  for (int i = 0; i < 3; i++){ v[i] = xr[tid + 256*i]; s += v[i]; }
  red[tid] = s; __syncthreads();
  for (int o = 128; o; o >>= 1){ if (tid < o) red[tid] += red[tid+o]; __syncthreads(); }
  float mean = red[0] * (1.f/768.f); __syncthreads();
  float s2 = 0.f;
  #pragma unroll
  for (int i = 0; i < 3; i++){ float d = v[i]-mean; s2 += d*d; }
  red[tid] = s2; __syncthreads();
  for (int o = 128; o; o >>= 1){ if (tid < o) red[tid] += red[tid+o]; __syncthreads(); }
  float rs = rsqrtf(red[0] * (1.f/768.f) + 1e-6f);
  const float* mb = mod + (long)b * 4608;
  #pragma unroll
  for (int i = 0; i < 3; i++){
    int d = tid + 256*i;
    y[(long)t*768 + d] = f2bf((1.f + mb[768+d]) * ((v[i]-mean)*rs) + mb[d]);
  }
}

// ---- h = x + g1*(pjA+pjB) ; y = (1+c2)*LN(h) + s2 ----
__global__ __launch_bounds__(256) void resid_ln_mod_kernel(const float* __restrict__ x,
    const float* __restrict__ pj, int pjoff, long pjspo, const float* __restrict__ mod,
    float* __restrict__ h, bf16* __restrict__ y, float* __restrict__ yf, int L){
  int t = blockIdx.x; int b = t / L;
  const float* mb = mod + (long)b * 4608;
  const float* xr = x + (long)t * 768;
  long pr = (long)(pjoff + b*1280 + (t % L)) * 768;
  __shared__ float red[256];
  int tid = threadIdx.x;
  float v[3]; float s = 0.f;
  #pragma unroll
  for (int i = 0; i < 3; i++){
    int d = tid + 256*i;
    float pv = pj[pr + d] + pj[pjspo + pr + d];
    float hv = xr[d] + mb[2*768 + d] * pv;
    h[(long)t*768 + d] = hv;
    v[i] = hv; s += hv;
  }
  red[tid] = s; __syncthreads();
  for (int o = 128; o; o >>= 1){ if (tid < o) red[tid] += red[tid+o]; __syncthreads(); }
  float mean = red[0] * (1.f/768.f); __syncthreads();
  float s2 = 0.f;
  #pragma unroll
  for (int i = 0; i < 3; i++){ float d = v[i]-mean; s2 += d*d; }
  red[tid] = s2; __syncthreads();
  for (int o = 128; o; o >>= 1){ if (tid < o) red[tid] += red[tid+o]; __syncthreads(); }
  float rs = rsqrtf(red[0] * (1.f/768.f) + 1e-6f);
  #pragma unroll
  for (int i = 0; i < 3; i++){
    int d = tid + 256*i;
    float val = (1.f + mb[4*768+d]) * ((v[i]-mean)*rs) + mb[3*768+d];
    y[(long)t*768 + d] = f2bf(val);
    yf[(long)t*768 + d] = val;
  }
}

// ---- qkv rows -> RMS-normed Q,K + transposed V ----
__global__ __launch_bounds__(256) void qkv_scatter_kernel(const bf16* __restrict__ qkv,
    const float* __restrict__ qs, const float* __restrict__ ks,
    bf16* __restrict__ Q, bf16* __restrict__ Kb, bf16* __restrict__ Vt,
    int L, int seqoff){
  __shared__ float vt[64][65];
  int bh = blockIdx.y;
  int b = bh / 12, hh = bh % 12;
  int st = blockIdx.x * 64;
  int w = threadIdx.x >> 6, lane = threadIdx.x & 63;
  float qsc = qs[lane], ksc = ks[lane];
  long qkvbase = (long)b * L * 2304;
  long outbase = (long)bh * 1280 * 64;
  #pragma unroll 4
  for (int i = 0; i < 16; i++){
    int r = w*16 + i;
    int t = st + r;
    const bf16* row = qkv + qkvbase + (long)t * 2304;
    float q = bf2f(row[hh*64 + lane]);
    float k = bf2f(row[768 + hh*64 + lane]);
    float v = bf2f(row[1536 + hh*64 + lane]);
    float q2 = q*q, k2 = k*k;
    for (int o = 32; o; o >>= 1){ q2 += __shfl_xor(q2, o); k2 += __shfl_xor(k2, o); }
    q = q * rsqrtf(q2*(1.f/64.f) + 1e-6f) * qsc;
    k = k * rsqrtf(k2*(1.f/64.f) + 1e-6f) * ksc;
    int seq = seqoff + t;
    Q [outbase + (long)seq*64 + lane] = f2bf(q);
    Kb[outbase + (long)seq*64 + lane] = f2bf(k);
    vt[r][lane] = v;
  }
  __syncthreads();
  #pragma unroll 4
  for (int i = 0; i < 16; i++){
    int d = w*16 + i;
    Vt[outbase + (long)d*1280 + seqoff + st + lane] = f2bf(vt[lane][d]);
  }
}

// ---- row softmax over 1280 (in-place safe) ----
__global__ __launch_bounds__(256) void softmax_kernel(const bf16* __restrict__ S, bf16* __restrict__ P){
  long r = blockIdx.x;
  const bf16* sr = S + r * 1280;
  __shared__ float buf[1280];
  __shared__ float red[256];
  int tid = threadIdx.x;
  float mx = -1e30f;
  for (int i = tid; i < 1280; i += 256){ float v = bf2f(sr[i]); buf[i] = v; mx = fmaxf(mx, v); }
  red[tid] = mx; __syncthreads();
  for (int o = 128; o; o >>= 1){ if (tid < o) red[tid] = fmaxf(red[tid], red[tid+o]); __syncthreads(); }
  float m = red[0]; __syncthreads();
  float s = 0.f;
  for (int i = tid; i < 1280; i += 256){ float e = expf(buf[i] - m); buf[i] = e; s += e; }
  red[tid] = s; __syncthreads();
  for (int o = 128; o; o >>= 1){ if (tid < o) red[tid] += red[tid+o]; __syncthreads(); }
  float inv = 1.f / red[0];
  bf16* pr = P + r * 1280;
  for (int i = tid; i < 1280; i += 256) pr[i] = f2bf(buf[i] * inv);
}

// ---- router ----
__global__ __launch_bounds__(256) void router_kernel(const float* __restrict__ x2,
    const float* __restrict__ gw, float* __restrict__ tkw, int* __restrict__ tki,
    int* __restrict__ counts, int T){
  int t = blockIdx.x * 4 + (threadIdx.x >> 6);
  int lane = threadIdx.x & 63;
  if (t >= T) return;
  const float* xr = x2 + (long)t * 768;
  float xs[12];
  #pragma unroll
  for (int i = 0; i < 12; i++) xs[i] = xr[lane + 64*i];
  float sc[8];
  #pragma unroll
  for (int e = 0; e < 8; e++){
    const float* gr = gw + e * 768;
    float p = 0.f;
    #pragma unroll
    for (int i = 0; i < 12; i++) p += xs[i] * gr[lane + 64*i];
    for (int o = 32; o; o >>= 1) p += __shfl_xor(p, o);
    sc[e] = p;
  }
  if (lane == 0){
    float m = sc[0];
    for (int e = 1; e < 8; e++) m = fmaxf(m, sc[e]);
    float s = 0.f;
    for (int e = 0; e < 8; e++){ sc[e] = expf(sc[e] - m); s += sc[e]; }
    float inv = 1.f / s;
    for (int e = 0; e < 8; e++) sc[e] *= inv;
    int i0 = 0;
    for (int e = 1; e < 8; e++) if (sc[e] > sc[i0]) i0 = e;
    int i1 = -1;
    for (int e = 0; e < 8; e++){ if (e == i0) continue; if (i1 < 0 || sc[e] > sc[i1]) i1 = e; }
    tkw[t*2] = sc[i0]; tkw[t*2+1] = sc[i1];
    tki[t*2] = i0;     tki[t*2+1] = i1;
    atomicAdd(&counts[i0], 1); atomicAdd(&counts[i1], 1);
  }
}

__global__ __launch_bounds__(256) void scatter_kernel(const int* __restrict__ tki,
    const int* __restrict__ ofs16, int* __restrict__ cur16,
    int* __restrict__ rows16, int* __restrict__ tpos, int T, int tabofs, int rowadd){
  int idx = blockIdx.x * 256 + threadIdx.x;
  if (idx >= T * 2) return;
  int t = idx >> 1;
  int e = tki[idx];
  int pos = atomicAdd(&cur16[tabofs + e], 1);
  int g = ofs16[tabofs + e] + pos;
  rows16[g] = rowadd + t;
  tpos[idx] = g;
}

// ---- out = h + g2 * (w0*sum8(ye_bf16)[p0] + w1*sum8(ye_bf16)[p1] + sum2(ys)) ----
__global__ __launch_bounds__(256) void combine_kernel(const float* __restrict__ h,
    const float* __restrict__ mod, const float* __restrict__ tkw, const int* __restrict__ tpos,
    const bf16* __restrict__ ye, long espo, const float* __restrict__ ys, long sspo,
    float* __restrict__ out, int L){
  int t = blockIdx.x; int b = t / L;
  const float* g2 = mod + (long)b * 4608 + 5*768;
  float w0 = tkw[t*2], w1 = tkw[t*2+1];
  long p0 = (long)tpos[t*2] * 768, p1 = (long)tpos[t*2+1] * 768;
  for (int d = threadIdx.x; d < 768; d += 256){
    float e0 = 0.f, e1 = 0.f, sv = 0.f;
    #pragma unroll
    for (int sp = 0; sp < 8; sp++){
      e0 += bf2f(ye[sp*espo + p0 + d]);
      e1 += bf2f(ye[sp*espo + p1 + d]);
    }
    #pragma unroll
    for (int sp = 0; sp < 2; sp++) sv += ys[sp*sspo + (long)t*768 + d];
    out[(long)t*768 + d] = h[(long)t*768 + d] + g2[d] * (w0*e0 + w1*e1 + sv);
  }
}

// =================================================================================
extern "C" void kernel_launch(void* const* d_in, const int* in_sizes, int n_in,
                              void* d_out, int out_size, void* d_ws, size_t ws_size,
                              hipStream_t stream){
  (void)in_sizes; (void)n_in; (void)out_size; (void)ws_size;
  const float* fin[33];
  for (int i = 0; i < 33; i++) fin[i] = (const float*)d_in[i];
  float* out_img = (float*)d_out;
  float* out_txt = (float*)d_out + (long)2*1024*768;

  char* ws = (char*)d_ws;
  size_t off = 0;
  auto alloc = [&](size_t n)->char*{
    off = (off + 255) & ~(size_t)255;
    char* p = ws + off; off += n; return p;
  };

  // ---- persistent ----
  float* mod_i=(float*)alloc(2*4608*4);
  float* mod_t=(float*)alloc(2*4608*4);
  float* h_i  =(float*)alloc((size_t)2048*768*4);
  float* h_t  =(float*)alloc((size_t)512*768*4);
  bf16*  x2c  =(bf16*) alloc((size_t)2560*768*2);
  float* x2fc =(float*)alloc((size_t)2560*768*4);
  float* tkw_i=(float*)alloc(2048*2*4);
  int*   tki_i=(int*)  alloc(2048*2*4);
  float* tkw_t=(float*)alloc(512*2*4);
  int*   tki_t=(int*)  alloc(512*2*4);
  int* cnt16=(int*)alloc(16*4);
  int* ofs16=(int*)alloc(16*4);
  int* cur16=(int*)alloc(16*4);
  int* rows16=(int*)alloc(5120*4);
  int* tpos_i=(int*)alloc(4096*4);
  int* tpos_t=(int*)alloc(1024*4);
  int* tabs=(int*)alloc(64*4);
  float* qb_ws=(float*)alloc(2*2304*4);
  float* pb_ws=(float*)alloc(2*768*4);

  size_t arena = (off + 255) & ~(size_t)255;
  // ---- phase A ----
  off = arena;
  bf16* Qb=(bf16*)alloc((size_t)24*1280*64*2);
  bf16* Kb=(bf16*)alloc((size_t)24*1280*64*2);
  bf16* Vt=(bf16*)alloc((size_t)24*1280*64*2);
  bf16* O =(bf16*)alloc((size_t)2*1280*768*2);
  float* pjc=(float*)alloc((size_t)2*2560*768*4);
  size_t sub = (off + 255) & ~(size_t)255;
  bf16* xmc=(bf16*)alloc((size_t)2560*768*2);
  bf16* qrc=(bf16*)alloc((size_t)2560*2304*2);
  off = sub;
  bf16* S=(bf16*)alloc((size_t)24*1280*1280*2);        // all 24 heads
  float* Opart=(float*)alloc((size_t)5*24*1280*64*4);  // PV split-5 partials
  // ---- phase B (overlays phase A) ----
  off = arena;
  bf16*  h1 =(bf16*) alloc((size_t)48*5120*64*2);    // kblk-major silu(g)*u
  bf16*  ye =(bf16*) alloc((size_t)8*5120*768*2);    // 8 k-split partials (bf16)
  bf16*  h1s=(bf16*) alloc((size_t)24*2560*64*2);    // kblk-major shared
  float* ys =(float*)alloc((size_t)2*2560*768*4);

  // bias concat copies (tiny)
  hipMemcpyAsync(qb_ws,      fin[8],  2304*4, hipMemcpyDeviceToDevice, stream);
  hipMemcpyAsync(qb_ws+2304, fin[12], 2304*4, hipMemcpyDeviceToDevice, stream);
  hipMemcpyAsync(pb_ws,      fin[14], 768*4,  hipMemcpyDeviceToDevice, stream);
  hipMemcpyAsync(pb_ws+768,  fin[10], 768*4,  hipMemcpyDeviceToDevice, stream);

  init_kernel<<<1, 64, 0, stream>>>(cnt16, tabs);
  mod_kernel<<<dim3(576,2), 256, 0, stream>>>(fin[2], fin[3], fin[4], mod_i);
  mod_kernel<<<dim3(576,2), 256, 0, stream>>>(fin[2], fin[5], fin[6], mod_t);
  ln_mod_kernel<<<2048, 256, 0, stream>>>(fin[0], mod_i, xmc, 1024);
  ln_mod_kernel<<<512,  256, 0, stream>>>(fin[1], mod_t, xmc + (long)2048*768, 256);

  // QKV: z=2 (img table 0, txt table 1); f32 B
  k_qkv<<<dim3(18,16,2), 256, 0, stream>>>(xmc, fin[7], fin[7], fin[11], fin[11],
      qb_ws, qrc, 0, 2304, 768, 768, 0, 0, 0, 2304, 2304,
      1, 0, 0, 2304, 1.f, 1, 0, nullptr, tabs+2, tabs+0);
  qkv_scatter_kernel<<<dim3(16,24), 256, 0, stream>>>(qrc, fin[15], fin[16], Qb, Kb, Vt, 1024, 256);
  qkv_scatter_kernel<<<dim3(4,24),  256, 0, stream>>>(qrc + (long)2048*2304, fin[17], fin[18], Qb, Kb, Vt, 256, 0);

  // attention: single pass, all 24 heads; softmax in-place; PV split-5
  k_qkt<<<dim3(10,10,24), 256, 0, stream>>>(Qb, Kb, Kb, Kb, Kb, nullptr, S,
      1280, 1280, 64, 64, (long)1280*64, (long)1280*64, 30, 0, 1280,
      1, (long)1280*1280, 0, 1280, 0.125f, 1, 0, nullptr, nullptr, nullptr);
  softmax_kernel<<<24*1280, 256, 0, stream>>>(S, S);
  k_pv<<<dim3(1,10,120), 256, 0, stream>>>(S, Vt, Vt, Vt, Vt, nullptr, Opart,
      1280, 64, 1280, 1280, (long)1280*1280, (long)64*1280, 30, 0, 64,
      1, (long)1280*64, 0, 64, 1.f, 5, (long)24*1280*64, nullptr, nullptr, nullptr);
  reduce_o_kernel<<<dim3(80,24), 256, 0, stream>>>(Opart, O, 24);

  // proj: z=4 tables, bidx=z>>1, ks=2 (f32 B)
  k_proj<<<dim3(6,8,8), 256, 0, stream>>>(O, fin[13], fin[13], fin[9], fin[9],
      pb_ws, pjc, 0, 768, 768, 768, 0, 0, 1, 768, 768,
      1, 0, 0, 768, 1.f, 2, (long)2560*768, nullptr, tabs+8, tabs+4);
  resid_ln_mod_kernel<<<2048, 256, 0, stream>>>(fin[0], pjc, 256, (long)2560*768,
      mod_i, h_i, x2c, x2fc, 1024);
  resid_ln_mod_kernel<<<512, 256, 0, stream>>>(fin[1], pjc, 0, (long)2560*768,
      mod_t, h_t, x2c + (long)2048*768, x2fc + (long)2048*768, 256);

  router_kernel<<<512, 256, 0, stream>>>(x2fc, fin[19], tkw_i, tki_i, cnt16, 2048);
  router_kernel<<<128, 256, 0, stream>>>(x2fc + (long)2048*768, fin[26], tkw_t, tki_t, cnt16+8, 512);
  tables_kernel<<<1, 1, 0, stream>>>(cnt16, ofs16, cur16);
  scatter_kernel<<<16, 256, 0, stream>>>(tki_i, ofs16, cur16, rows16, tpos_i, 2048, 0, 0);
  scatter_kernel<<<4,  256, 0, stream>>>(tki_t, ofs16, cur16, rows16, tpos_t, 512, 8, 2048);

  // expert gate/up pair-interleaved -> kblk-major h1 (m-pair blocks: B reused via L2)
  k_gup<<<dim3(48,8,16), 256, 0, stream>>>(x2c, fin[20], fin[21], fin[27], fin[28],
      nullptr, h1, 0, 6144, 768, 768, 0, (long)3072*768, 3, 0, 0,
      1, 0, 0, 5120, 1.f, 1, 0, rows16, ofs16, cnt16);
  // expert down: A = h1 kblk-major (lda=5120), K=3072, ks=8 (m-pair blocks)
  k_down<<<dim3(6,8,128), 256, 0, stream>>>(h1, fin[22], fin[22], fin[29], fin[29],
      nullptr, ye, 0, 768, 3072, 5120, 0, (long)768*3072, 3, 0, 768,
      1, 0, 0, 768, 1.f, 8, (long)5120*768, nullptr, ofs16, cnt16);
  // shared gate/up pair-interleaved -> kblk-major h1s (Mtot = 2560)
  k_sgup<<<dim3(24,16,2), 256, 0, stream>>>(x2c, fin[23], fin[24], fin[30], fin[31],
      nullptr, h1s, 0, 3072, 768, 768, 0, 0, 0, 0, 0,
      1, 0, 0, 2560, 1.f, 1, 0, nullptr, tabs+14, tabs+12);
  // shared down: A = h1s kblk-major (lda = 2560), K=1536, ks=2
  k_sdown<<<dim3(6,16,4), 256, 0, stream>>>(h1s, fin[25], fin[25], fin[32], fin[32],
      nullptr, ys, 0, 768, 1536, 2560, 0, 0, 0, 0, 768,
      1, 0, 0, 768, 1.f, 2, (long)2560*768, nullptr, tabs+14, tabs+12);

  combine_kernel<<<2048, 256, 0, stream>>>(h_i, mod_i, tkw_i, tpos_i,
      ye, (long)5120*768, ys, (long)2560*768, out_img, 1024);
  combine_kernel<<<512, 256, 0, stream>>>(h_t, mod_t, tkw_t, tpos_t,
      ye, (long)5120*768, ys + (long)2048*768, (long)2560*768, out_txt, 256);
}

// Round 17
// 1063.588 us; speedup vs baseline: 1.0511x; 1.0511x over previous
//
#include <hip/hip_runtime.h>
#include <hip/hip_bf16.h>

using bf16 = __hip_bfloat16;
typedef __attribute__((ext_vector_type(4))) float f32x4;
typedef __attribute__((ext_vector_type(8))) short s16x8;

#define DEV static __device__ __forceinline__
DEV float bf2f(bf16 x){ return __bfloat162float(x); }
DEV bf16  f2bf(float x){ return __float2bfloat16(x); }
DEV float silu_(float x){ return x / (1.f + expf(-x)); }
// 16B-block XOR swizzle inside a 128x64 bf16 tile (row stride 64 elems = 8 blocks)
DEV int swz(int row, int colEl){ return row*64 + ((((colEl) >> 3) ^ (row & 7)) << 3); }

// ------------------------------------------------------------------
// Pipelined bf16 MFMA GEMM core:  C = alpha * (A @ B^T) (+ bias)
// A bf16. ABLK: A stored kblk-major [k/64][Mtot(=lda)][64] (h1 layout).
// B f32 or bf16. bidx = z>>bshift picks {B0*,B1*}; PAIRB: B row r ->
// (r&1 ? upper : lower)[r>>1]; else row >= nsplitB uses upper at
// row-nsplitB. e = z & mask strides by b_zoff. EXPERT: Meff=counts[z],
// rowbase=offsets[z]; GATHER via rowlist. OUT: 0=f32, 1=bf16,
// 3=pair-epilogue silu(even)*odd -> bf16 into kblk-major [n0/128][ldc=Mtot][64].
// LDS: unpadded 128x64 tiles with XOR-16B swizzle (32 KB total -> 5 blocks/CU).
// ksplit: z=zz/ksplit, split writes +split*c_spo.
// ------------------------------------------------------------------
template<bool B_F32, bool EXPERT, bool GATHER, int OUT, bool BIAS, bool PAIRB, bool ABLK>
DEV void gemm_core(
    const bf16* __restrict__ A,
    const void* __restrict__ B0a, const void* __restrict__ B0b,
    const void* __restrict__ B1a, const void* __restrict__ B1b,
    const float* __restrict__ bias, void* __restrict__ C,
    int M, int N, int K, int lda,
    long a_zoff, long b_zoff, int bshift, int biasz, int nsplitB,
    int zdiv, long c_so, long c_si, int ldc,
    float alpha, int ksplit, long c_spo,
    const int* __restrict__ rowlist, const int* __restrict__ offsets,
    const int* __restrict__ counts)
{
  __shared__ __align__(16) char smem_[32768];
  bf16* As = (bf16*)smem_;
  bf16* Bs = (bf16*)(smem_ + 16384);
  float (*st)[132] = (float(*)[132])smem_;   // 16896 B, reused post-loop

  const int zz = blockIdx.z;
  const int n0 = blockIdx.x * 128;
  const int z = zz / ksplit, split = zz % ksplit;
  int Meff = M; long rowbase = 0;
  if (EXPERT){ Meff = counts[z]; rowbase = offsets[z]; }
  const int m0 = blockIdx.y * 128;
  if (m0 >= Meff) return;
  const bf16* Ab = A + (EXPERT ? 0 : z * a_zoff);
  const int bidx = z >> bshift;
  const long e = (long)(z & ((1 << bshift) - 1));
  const void* BL = bidx ? B1a : B0a;
  const void* BU = bidx ? B1b : B0b;
  long coff;
  if (EXPERT) coff = rowbase * (long)ldc;
  else        coff = (long)(z / zdiv) * c_so + (long)(z % zdiv) * c_si;
  coff += (long)split * c_spo;
  const float* bias_eff = BIAS ? bias + (long)bidx * biasz : nullptr;

  const int klen = K / ksplit;
  const int kbeg = split * klen;
  const int NT = klen >> 6;

  const int tid = threadIdx.x;
  const int lane = tid & 63, wid = tid >> 6;
  const int wm = wid >> 1, wn = wid & 1;
  const int rbase = tid >> 3;
  const int kc = (tid & 7) << 3;

  // ---- B pointers ----
  const bf16* bp[4]; const float* bpf[4];
  bool bvalid[4];
  #pragma unroll
  for (int it = 0; it < 4; it++){
    int br = n0 + rbase + 32 * it;
    bvalid[it] = br < N;
    int brc = bvalid[it] ? br : 0;
    const void* Bsel; long brr;
    if (PAIRB){ Bsel = (brc & 1) ? BU : BL; brr = brc >> 1; }
    else { bool up = brc >= nsplitB; Bsel = up ? BU : BL; brr = up ? (brc - nsplitB) : brc; }
    if (B_F32) bpf[it] = (const float*)Bsel + e * b_zoff + brr * K + kbeg + kc;
    else       bp[it]  = (const bf16*) Bsel + e * b_zoff + brr * K + kbeg + kc;
  }
  // ---- A pointers ----
  const bf16* ap[4];
  bool avalid[4];
  #pragma unroll
  for (int it = 0; it < 4; it++){
    int row = rbase + 32 * it;
    long ar = 0;
    if (EXPERT){
      int i = m0 + row;
      avalid[it] = i < Meff;
      if (avalid[it]) ar = GATHER ? (long)rowlist[rowbase + i] : (rowbase + i);
    } else {
      avalid[it] = (m0 + row) < Meff;
      ar = m0 + row;
    }
    if (ABLK) ap[it] = Ab + ((long)(kbeg >> 6) * lda + ar) * 64 + kc;
    else      ap[it] = Ab + ar * (long)lda + kbeg + kc;
  }

  const uint4 zero4 = make_uint4(0u,0u,0u,0u);
  uint4 ra[4], rb[4];
  float4 fb0[4], fb1[4];

  auto LOAD = [&](int koff){
    long aoff = ABLK ? (long)koff * lda : (long)koff;
    #pragma unroll
    for (int it = 0; it < 4; it++){
      ra[it] = avalid[it] ? *(const uint4*)(ap[it] + aoff) : zero4;
      if (B_F32){
        if (bvalid[it]){ fb0[it] = *(const float4*)(bpf[it] + koff);
                         fb1[it] = *(const float4*)(bpf[it] + koff + 4); }
        else { fb0[it] = make_float4(0,0,0,0); fb1[it] = make_float4(0,0,0,0); }
      } else {
        rb[it] = bvalid[it] ? *(const uint4*)(bp[it] + koff) : zero4;
      }
    }
  };
  auto STORE = [&](){
    #pragma unroll
    for (int it = 0; it < 4; it++){
      int row = rbase + 32 * it;
      *(uint4*)(As + swz(row, kc)) = ra[it];
      if (B_F32){
        union { bf16 h[8]; uint4 v; } u;
        u.h[0]=f2bf(fb0[it].x); u.h[1]=f2bf(fb0[it].y); u.h[2]=f2bf(fb0[it].z); u.h[3]=f2bf(fb0[it].w);
        u.h[4]=f2bf(fb1[it].x); u.h[5]=f2bf(fb1[it].y); u.h[6]=f2bf(fb1[it].z); u.h[7]=f2bf(fb1[it].w);
        *(uint4*)(Bs + swz(row, kc)) = u.v;
      } else {
        *(uint4*)(Bs + swz(row, kc)) = rb[it];
      }
    }
  };

  f32x4 acc[4][4] = {};
  LOAD(0);
  for (int t = 0; t < NT; t++){
    STORE();
    __syncthreads();
    if (t + 1 < NT) LOAD((t + 1) << 6);
    #pragma unroll
    for (int ks2 = 0; ks2 < 2; ks2++){
      const int r16 = lane & 15;
      const int kk = ks2 * 32 + ((lane >> 4) << 3);
      s16x8 af[4], bfr[4];
      #pragma unroll
      for (int mi = 0; mi < 4; mi++) af[mi]  = *(const s16x8*)(As + swz(wm*64 + mi*16 + r16, kk));
      #pragma unroll
      for (int ni = 0; ni < 4; ni++) bfr[ni] = *(const s16x8*)(Bs + swz(wn*64 + ni*16 + r16, kk));
      #pragma unroll
      for (int mi = 0; mi < 4; mi++)
        #pragma unroll
        for (int ni = 0; ni < 4; ni++)
          acc[mi][ni] = __builtin_amdgcn_mfma_f32_16x16x32_bf16(af[mi], bfr[ni], acc[mi][ni], 0, 0, 0);
    }
    __syncthreads();
  }

  // ---- LDS-staged coalesced epilogue ----
  const int er = tid >> 3;
  const int ec = (tid & 7) << 4;
  const int erg = m0 + (er & 15) + ((er & 16) ? 64 : 0);
  #pragma unroll
  for (int mi = 0; mi < 4; mi++){
    #pragma unroll
    for (int ni = 0; ni < 4; ni++){
      int lc = wn*64 + ni*16 + (lane & 15);
      float bv = 0.f;
      if (BIAS){ if (split == 0) bv = bias_eff[n0 + lc]; }
      #pragma unroll
      for (int i = 0; i < 4; i++){
        int lr = wm*16 + ((lane >> 4) << 2) + i;
        st[lr][lc] = acc[mi][ni][i] * alpha + bv;
      }
    }
    __syncthreads();
    int rg = erg + mi*16;
    if (rg < Meff){
      if (OUT == 3){
        long base = ((long)(n0 >> 7) * (long)ldc + rowbase + rg) * 64 + (ec >> 1);
        union { bf16 h[8]; uint4 v; } o;
        #pragma unroll
        for (int j = 0; j < 8; j++)
          o.h[j] = f2bf(silu_(st[er][ec + 2*j]) * st[er][ec + 2*j + 1]);
        *(uint4*)((bf16*)C + base) = o.v;
      } else {
        int cg = n0 + ec;
        if (cg < N){
          long base = coff + (long)rg * ldc + cg;
          if (OUT == 0){
            float* dst = (float*)C + base;
            #pragma unroll
            for (int q = 0; q < 4; q++)
              *(float4*)(dst + 4*q) = make_float4(st[er][ec+4*q], st[er][ec+4*q+1],
                                                  st[er][ec+4*q+2], st[er][ec+4*q+3]);
          } else {
            union { bf16 h[8]; uint4 v; } o0, o1;
            #pragma unroll
            for (int j = 0; j < 8; j++){
              o0.h[j] = f2bf(st[er][ec+j]);
              o1.h[j] = f2bf(st[er][ec+8+j]);
            }
            *(uint4*)((bf16*)C + base)     = o0.v;
            *(uint4*)((bf16*)C + base + 8) = o1.v;
          }
        }
      }
    }
    __syncthreads();
  }
}

#define GEMM_K(NAME, BF32, EXPERT, GATHER, OUT, BIAS, PAIRB, ABLK)                 \
__global__ __launch_bounds__(256) void NAME(                                       \
    const bf16* A, const void* B0a, const void* B0b, const void* B1a,              \
    const void* B1b, const float* bias, void* C,                                   \
    int M, int N, int K, int lda, long az, long bz, int bshift, int biasz,         \
    int nsplitB, int zdiv, long cso, long csi, int ldc, float alpha, int ks,       \
    long cspo, const int* rl, const int* ofs, const int* cnt){                     \
  gemm_core<BF32,EXPERT,GATHER,OUT,BIAS,PAIRB,ABLK>(A,B0a,B0b,B1a,B1b,bias,C,      \
      M,N,K,lda,az,bz,bshift,biasz,nsplitB,zdiv,cso,csi,ldc,alpha,ks,cspo,rl,ofs,cnt); }

GEMM_K(k_qkv,  true ,true ,false,1,true ,false,false)
GEMM_K(k_qkt,  false,false,false,1,false,false,false)
GEMM_K(k_pv,   false,false,false,0,false,false,false)
GEMM_K(k_proj, true ,true ,false,0,true ,false,false)
GEMM_K(k_gup,  true ,true ,true ,3,false,true ,false)
GEMM_K(k_down, true ,true ,false,1,false,false,true )
GEMM_K(k_sgup, true ,true ,false,3,false,true ,false)
GEMM_K(k_sdown,true ,true ,false,0,false,false,true )

// ---- init / tables ----
__global__ void init_kernel(int* cnt16, int* tabs){
  int i = threadIdx.x;
  if (i < 16) cnt16[i] = 0;
  if (i == 0){
    tabs[0]=2048; tabs[1]=512; tabs[2]=0; tabs[3]=2048;          // qkv cnt/ofs
    tabs[4]=256; tabs[5]=256; tabs[6]=1024; tabs[7]=1024;        // proj cnt
    tabs[8]=0; tabs[9]=1280; tabs[10]=256; tabs[11]=1536;        // proj ofs
    tabs[12]=2048; tabs[13]=512; tabs[14]=0; tabs[15]=2048;      // shared cnt/ofs
  }
}
__global__ void tables_kernel(const int* cnt16, int* ofs16, int* cur16){
  if (threadIdx.x == 0){
    int o = 0;
    for (int e = 0; e < 8; e++){ ofs16[e] = o; o += cnt16[e]; cur16[e] = 0; }
    o = 4096;
    for (int e = 8; e < 16; e++){ ofs16[e] = o; o += cnt16[e]; cur16[e] = 0; }
  }
}

// ---- O partial reduce: Opart[5][NH][1280][64] f32 -> O bf16 ----
__global__ __launch_bounds__(256) void reduce_o_kernel(const float* __restrict__ Op,
    bf16* __restrict__ O, int nh){
  int bh = blockIdx.y;
  int b = bh / 12, hh = bh % 12;
  int d = threadIdx.x & 63, rr = threadIdx.x >> 6;
  const float* base = Op + (long)bh * 1280 * 64;
  #pragma unroll
  for (int j = 0; j < 4; j++){
    int row = blockIdx.x * 16 + rr * 4 + j;
    float s = 0.f;
    #pragma unroll
    for (int sp = 0; sp < 5; sp++) s += base[(long)sp*nh*1280*64 + (long)row*64 + d];
    O[((long)b*1280 + row)*768 + hh*64 + d] = f2bf(s);
  }
}

// ---- modulation GEMV ----
__global__ __launch_bounds__(256) void mod_kernel(const float* __restrict__ vec,
    const float* __restrict__ w, const float* __restrict__ b, float* __restrict__ out){
  int bb = blockIdx.y;
  __shared__ float sv[768];
  int tid = threadIdx.x;
  for (int i = tid; i < 768; i += 256){ float v = vec[bb*768 + i]; sv[i] = v/(1.f+expf(-v)); }
  __syncthreads();
  int w4 = tid >> 6, lane = tid & 63;
  int j0 = blockIdx.x * 8 + w4 * 2;
  for (int jj = 0; jj < 2; jj++){
    int j = j0 + jj;
    const float* wr = w + (long)j * 768;
    float p = 0.f;
    #pragma unroll
    for (int i = 0; i < 12; i++) p += sv[lane + 64*i] * wr[lane + 64*i];
    for (int o = 32; o; o >>= 1) p += __shfl_xor(p, o);
    if (lane == 0) out[bb*4608 + j] = p + b[j];
  }
}

// ---- y = (1+c)*LN(x) + s ----
__global__ __launch_bounds__(256) void ln_mod_kernel(const float* __restrict__ x,
    const float* __restrict__ mod, bf16* __restrict__ y, int L){
  int t = blockIdx.x; int b = t / L;
  const float* xr = x + (long)t * 768;
  __shared__ float red[256];
  int tid = threadIdx.x;
  float v[3]; float s = 0.f;
  #pragma unroll
  for (int i = 0; i < 3; i++){ v[i] = xr[tid + 256*i]; s += v[i]; }
  red[tid] = s; __syncthreads();
  for (int o = 128; o; o >>= 1){ if (tid < o) red[tid] += red[tid+o]; __syncthreads(); }
  float mean = red[0] * (1.f/768.f); __syncthreads();
  float s2 = 0.f;
  #pragma unroll
  for (int i = 0; i < 3; i++){ float d = v[i]-mean; s2 += d*d; }
  red[tid] = s2; __syncthreads();
  for (int o = 128; o; o >>= 1){ if (tid < o) red[tid] += red[tid+o]; __syncthreads(); }
  float rs = rsqrtf(red[0] * (1.f/768.f) + 1e-6f);
  const float* mb = mod + (long)b * 4608;
  #pragma unroll
  for (int i = 0; i < 3; i++){
    int d = tid + 256*i;
    y[(long)t*768 + d] = f2bf((1.f + mb[768+d]) * ((v[i]-mean)*rs) + mb[d]);
  }
}

// ---- h = x + g1*(pjA+pjB) ; y = (1+c2)*LN(h) + s2 ----
__global__ __launch_bounds__(256) void resid_ln_mod_kernel(const float* __restrict__ x,
    const float* __restrict__ pj, int pjoff, long pjspo, const float* __restrict__ mod,
    float* __restrict__ h, bf16* __restrict__ y, float* __restrict__ yf, int L){
  int t = blockIdx.x; int b = t / L;
  const float* mb = mod + (long)b * 4608;
  const float* xr = x + (long)t * 768;
  long pr = (long)(pjoff + b*1280 + (t % L)) * 768;
  __shared__ float red[256];
  int tid = threadIdx.x;
  float v[3]; float s = 0.f;
  #pragma unroll
  for (int i = 0; i < 3; i++){
    int d = tid + 256*i;
    float pv = pj[pr + d] + pj[pjspo + pr + d];
    float hv = xr[d] + mb[2*768 + d] * pv;
    h[(long)t*768 + d] = hv;
    v[i] = hv; s += hv;
  }
  red[tid] = s; __syncthreads();
  for (int o = 128; o; o >>= 1){ if (tid < o) red[tid] += red[tid+o]; __syncthreads(); }
  float mean = red[0] * (1.f/768.f); __syncthreads();
  float s2 = 0.f;
  #pragma unroll
  for (int i = 0; i < 3; i++){ float d = v[i]-mean; s2 += d*d; }
  red[tid] = s2; __syncthreads();
  for (int o = 128; o; o >>= 1){ if (tid < o) red[tid] += red[tid+o]; __syncthreads(); }
  float rs = rsqrtf(red[0] * (1.f/768.f) + 1e-6f);
  #pragma unroll
  for (int i = 0; i < 3; i++){
    int d = tid + 256*i;
    float val = (1.f + mb[4*768+d]) * ((v[i]-mean)*rs) + mb[3*768+d];
    y[(long)t*768 + d] = f2bf(val);
    yf[(long)t*768 + d] = val;
  }
}

// ---- qkv rows -> RMS-normed Q,K + transposed V ----
__global__ __launch_bounds__(256) void qkv_scatter_kernel(const bf16* __restrict__ qkv,
    const float* __restrict__ qs, const float* __restrict__ ks,
    bf16* __restrict__ Q, bf16* __restrict__ Kb, bf16* __restrict__ Vt,
    int L, int seqoff){
  __shared__ float vt[64][65];
  int bh = blockIdx.y;
  int b = bh / 12, hh = bh % 12;
  int st = blockIdx.x * 64;
  int w = threadIdx.x >> 6, lane = threadIdx.x & 63;
  float qsc = qs[lane], ksc = ks[lane];
  long qkvbase = (long)b * L * 2304;
  long outbase = (long)bh * 1280 * 64;
  #pragma unroll 4
  for (int i = 0; i < 16; i++){
    int r = w*16 + i;
    int t = st + r;
    const bf16* row = qkv + qkvbase + (long)t * 2304;
    float q = bf2f(row[hh*64 + lane]);
    float k = bf2f(row[768 + hh*64 + lane]);
    float v = bf2f(row[1536 + hh*64 + lane]);
    float q2 = q*q, k2 = k*k;
    for (int o = 32; o; o >>= 1){ q2 += __shfl_xor(q2, o); k2 += __shfl_xor(k2, o); }
    q = q * rsqrtf(q2*(1.f/64.f) + 1e-6f) * qsc;
    k = k * rsqrtf(k2*(1.f/64.f) + 1e-6f) * ksc;
    int seq = seqoff + t;
    Q [outbase + (long)seq*64 + lane] = f2bf(q);
    Kb[outbase + (long)seq*64 + lane] = f2bf(k);
    vt[r][lane] = v;
  }
  __syncthreads();
  #pragma unroll 4
  for (int i = 0; i < 16; i++){
    int d = w*16 + i;
    Vt[outbase + (long)d*1280 + seqoff + st + lane] = f2bf(vt[lane][d]);
  }
}

// ---- row softmax over 1280 (in-place safe) ----
__global__ __launch_bounds__(256) void softmax_kernel(const bf16* __restrict__ S, bf16* __restrict__ P){
  long r = blockIdx.x;
  const bf16* sr = S + r * 1280;
  __shared__ float buf[1280];
  __shared__ float red[256];
  int tid = threadIdx.x;
  float mx = -1e30f;
  for (int i = tid; i < 1280; i += 256){ float v = bf2f(sr[i]); buf[i] = v; mx = fmaxf(mx, v); }
  red[tid] = mx; __syncthreads();
  for (int o = 128; o; o >>= 1){ if (tid < o) red[tid] = fmaxf(red[tid], red[tid+o]); __syncthreads(); }
  float m = red[0]; __syncthreads();
  float s = 0.f;
  for (int i = tid; i < 1280; i += 256){ float e = expf(buf[i] - m); buf[i] = e; s += e; }
  red[tid] = s; __syncthreads();
  for (int o = 128; o; o >>= 1){ if (tid < o) red[tid] += red[tid+o]; __syncthreads(); }
  float inv = 1.f / red[0];
  bf16* pr = P + r * 1280;
  for (int i = tid; i < 1280; i += 256) pr[i] = f2bf(buf[i] * inv);
}

// ---- router ----
__global__ __launch_bounds__(256) void router_kernel(const float* __restrict__ x2,
    const float* __restrict__ gw, float* __restrict__ tkw, int* __restrict__ tki,
    int* __restrict__ counts, int T){
  int t = blockIdx.x * 4 + (threadIdx.x >> 6);
  int lane = threadIdx.x & 63;
  if (t >= T) return;
  const float* xr = x2 + (long)t * 768;
  float xs[12];
  #pragma unroll
  for (int i = 0; i < 12; i++) xs[i] = xr[lane + 64*i];
  float sc[8];
  #pragma unroll
  for (int e = 0; e < 8; e++){
    const float* gr = gw + e * 768;
    float p = 0.f;
    #pragma unroll
    for (int i = 0; i < 12; i++) p += xs[i] * gr[lane + 64*i];
    for (int o = 32; o; o >>= 1) p += __shfl_xor(p, o);
    sc[e] = p;
  }
  if (lane == 0){
    float m = sc[0];
    for (int e = 1; e < 8; e++) m = fmaxf(m, sc[e]);
    float s = 0.f;
    for (int e = 0; e < 8; e++){ sc[e] = expf(sc[e] - m); s += sc[e]; }
    float inv = 1.f / s;
    for (int e = 0; e < 8; e++) sc[e] *= inv;
    int i0 = 0;
    for (int e = 1; e < 8; e++) if (sc[e] > sc[i0]) i0 = e;
    int i1 = -1;
    for (int e = 0; e < 8; e++){ if (e == i0) continue; if (i1 < 0 || sc[e] > sc[i1]) i1 = e; }
    tkw[t*2] = sc[i0]; tkw[t*2+1] = sc[i1];
    tki[t*2] = i0;     tki[t*2+1] = i1;
    atomicAdd(&counts[i0], 1); atomicAdd(&counts[i1], 1);
  }
}

__global__ __launch_bounds__(256) void scatter_kernel(const int* __restrict__ tki,
    const int* __restrict__ ofs16, int* __restrict__ cur16,
    int* __restrict__ rows16, int* __restrict__ tpos, int T, int tabofs, int rowadd){
  int idx = blockIdx.x * 256 + threadIdx.x;
  if (idx >= T * 2) return;
  int t = idx >> 1;
  int e = tki[idx];
  int pos = atomicAdd(&cur16[tabofs + e], 1);
  int g = ofs16[tabofs + e] + pos;
  rows16[g] = rowadd + t;
  tpos[idx] = g;
}

// ---- out = h + g2 * (w0*sum8(ye_bf16)[p0] + w1*sum8(ye_bf16)[p1] + sum2(ys)) ----
__global__ __launch_bounds__(256) void combine_kernel(const float* __restrict__ h,
    const float* __restrict__ mod, const float* __restrict__ tkw, const int* __restrict__ tpos,
    const bf16* __restrict__ ye, long espo, const float* __restrict__ ys, long sspo,
    float* __restrict__ out, int L){
  int t = blockIdx.x; int b = t / L;
  const float* g2 = mod + (long)b * 4608 + 5*768;
  float w0 = tkw[t*2], w1 = tkw[t*2+1];
  long p0 = (long)tpos[t*2] * 768, p1 = (long)tpos[t*2+1] * 768;
  for (int d = threadIdx.x; d < 768; d += 256){
    float e0 = 0.f, e1 = 0.f, sv = 0.f;
    #pragma unroll
    for (int sp = 0; sp < 8; sp++){
      e0 += bf2f(ye[sp*espo + p0 + d]);
      e1 += bf2f(ye[sp*espo + p1 + d]);
    }
    #pragma unroll
    for (int sp = 0; sp < 2; sp++) sv += ys[sp*sspo + (long)t*768 + d];
    out[(long)t*768 + d] = h[(long)t*768 + d] + g2[d] * (w0*e0 + w1*e1 + sv);
  }
}

// =================================================================================
extern "C" void kernel_launch(void* const* d_in, const int* in_sizes, int n_in,
                              void* d_out, int out_size, void* d_ws, size_t ws_size,
                              hipStream_t stream){
  (void)in_sizes; (void)n_in; (void)out_size; (void)ws_size;
  const float* fin[33];
  for (int i = 0; i < 33; i++) fin[i] = (const float*)d_in[i];
  float* out_img = (float*)d_out;
  float* out_txt = (float*)d_out + (long)2*1024*768;

  char* ws = (char*)d_ws;
  size_t off = 0;
  auto alloc = [&](size_t n)->char*{
    off = (off + 255) & ~(size_t)255;
    char* p = ws + off; off += n; return p;
  };

  // ---- persistent ----
  float* mod_i=(float*)alloc(2*4608*4);
  float* mod_t=(float*)alloc(2*4608*4);
  float* h_i  =(float*)alloc((size_t)2048*768*4);
  float* h_t  =(float*)alloc((size_t)512*768*4);
  bf16*  x2c  =(bf16*) alloc((size_t)2560*768*2);
  float* x2fc =(float*)alloc((size_t)2560*768*4);
  float* tkw_i=(float*)alloc(2048*2*4);
  int*   tki_i=(int*)  alloc(2048*2*4);
  float* tkw_t=(float*)alloc(512*2*4);
  int*   tki_t=(int*)  alloc(512*2*4);
  int* cnt16=(int*)alloc(16*4);
  int* ofs16=(int*)alloc(16*4);
  int* cur16=(int*)alloc(16*4);
  int* rows16=(int*)alloc(5120*4);
  int* tpos_i=(int*)alloc(4096*4);
  int* tpos_t=(int*)alloc(1024*4);
  int* tabs=(int*)alloc(64*4);
  float* qb_ws=(float*)alloc(2*2304*4);
  float* pb_ws=(float*)alloc(2*768*4);

  size_t arena = (off + 255) & ~(size_t)255;
  // ---- phase A ----
  off = arena;
  bf16* Qb=(bf16*)alloc((size_t)24*1280*64*2);
  bf16* Kb=(bf16*)alloc((size_t)24*1280*64*2);
  bf16* Vt=(bf16*)alloc((size_t)24*1280*64*2);
  bf16* O =(bf16*)alloc((size_t)2*1280*768*2);
  float* pjc=(float*)alloc((size_t)2*2560*768*4);
  size_t sub = (off + 255) & ~(size_t)255;
  bf16* xmc=(bf16*)alloc((size_t)2560*768*2);
  bf16* qrc=(bf16*)alloc((size_t)2560*2304*2);
  off = sub;
  bf16* S=(bf16*)alloc((size_t)24*1280*1280*2);        // all 24 heads
  float* Opart=(float*)alloc((size_t)5*24*1280*64*4);  // PV split-5 partials
  // ---- phase B (overlays phase A) ----
  off = arena;
  bf16*  h1 =(bf16*) alloc((size_t)48*5120*64*2);    // kblk-major silu(g)*u
  bf16*  ye =(bf16*) alloc((size_t)8*5120*768*2);    // 8 k-split partials (bf16)
  bf16*  h1s=(bf16*) alloc((size_t)24*2560*64*2);    // kblk-major shared
  float* ys =(float*)alloc((size_t)2*2560*768*4);

  // bias concat copies (tiny)
  hipMemcpyAsync(qb_ws,      fin[8],  2304*4, hipMemcpyDeviceToDevice, stream);
  hipMemcpyAsync(qb_ws+2304, fin[12], 2304*4, hipMemcpyDeviceToDevice, stream);
  hipMemcpyAsync(pb_ws,      fin[14], 768*4,  hipMemcpyDeviceToDevice, stream);
  hipMemcpyAsync(pb_ws+768,  fin[10], 768*4,  hipMemcpyDeviceToDevice, stream);

  init_kernel<<<1, 64, 0, stream>>>(cnt16, tabs);
  mod_kernel<<<dim3(576,2), 256, 0, stream>>>(fin[2], fin[3], fin[4], mod_i);
  mod_kernel<<<dim3(576,2), 256, 0, stream>>>(fin[2], fin[5], fin[6], mod_t);
  ln_mod_kernel<<<2048, 256, 0, stream>>>(fin[0], mod_i, xmc, 1024);
  ln_mod_kernel<<<512,  256, 0, stream>>>(fin[1], mod_t, xmc + (long)2048*768, 256);

  // QKV: z=2 (img table 0, txt table 1); f32 B
  k_qkv<<<dim3(18,16,2), 256, 0, stream>>>(xmc, fin[7], fin[7], fin[11], fin[11],
      qb_ws, qrc, 0, 2304, 768, 768, 0, 0, 0, 2304, 2304,
      1, 0, 0, 2304, 1.f, 1, 0, nullptr, tabs+2, tabs+0);
  qkv_scatter_kernel<<<dim3(16,24), 256, 0, stream>>>(qrc, fin[15], fin[16], Qb, Kb, Vt, 1024, 256);
  qkv_scatter_kernel<<<dim3(4,24),  256, 0, stream>>>(qrc + (long)2048*2304, fin[17], fin[18], Qb, Kb, Vt, 256, 0);

  // attention: single pass, all 24 heads; softmax in-place; PV split-5
  k_qkt<<<dim3(10,10,24), 256, 0, stream>>>(Qb, Kb, Kb, Kb, Kb, nullptr, S,
      1280, 1280, 64, 64, (long)1280*64, (long)1280*64, 30, 0, 1280,
      1, (long)1280*1280, 0, 1280, 0.125f, 1, 0, nullptr, nullptr, nullptr);
  softmax_kernel<<<24*1280, 256, 0, stream>>>(S, S);
  k_pv<<<dim3(1,10,120), 256, 0, stream>>>(S, Vt, Vt, Vt, Vt, nullptr, Opart,
      1280, 64, 1280, 1280, (long)1280*1280, (long)64*1280, 30, 0, 64,
      1, (long)1280*64, 0, 64, 1.f, 5, (long)24*1280*64, nullptr, nullptr, nullptr);
  reduce_o_kernel<<<dim3(80,24), 256, 0, stream>>>(Opart, O, 24);

  // proj: z=4 tables, bidx=z>>1, ks=2 (f32 B)
  k_proj<<<dim3(6,8,8), 256, 0, stream>>>(O, fin[13], fin[13], fin[9], fin[9],
      pb_ws, pjc, 0, 768, 768, 768, 0, 0, 1, 768, 768,
      1, 0, 0, 768, 1.f, 2, (long)2560*768, nullptr, tabs+8, tabs+4);
  resid_ln_mod_kernel<<<2048, 256, 0, stream>>>(fin[0], pjc, 256, (long)2560*768,
      mod_i, h_i, x2c, x2fc, 1024);
  resid_ln_mod_kernel<<<512, 256, 0, stream>>>(fin[1], pjc, 0, (long)2560*768,
      mod_t, h_t, x2c + (long)2048*768, x2fc + (long)2048*768, 256);

  router_kernel<<<512, 256, 0, stream>>>(x2fc, fin[19], tkw_i, tki_i, cnt16, 2048);
  router_kernel<<<128, 256, 0, stream>>>(x2fc + (long)2048*768, fin[26], tkw_t, tki_t, cnt16+8, 512);
  tables_kernel<<<1, 1, 0, stream>>>(cnt16, ofs16, cur16);
  scatter_kernel<<<16, 256, 0, stream>>>(tki_i, ofs16, cur16, rows16, tpos_i, 2048, 0, 0);
  scatter_kernel<<<4,  256, 0, stream>>>(tki_t, ofs16, cur16, rows16, tpos_t, 512, 8, 2048);

  // expert gate/up pair-interleaved -> kblk-major h1 (per-m-tile grid, early exit)
  k_gup<<<dim3(48,16,16), 256, 0, stream>>>(x2c, fin[20], fin[21], fin[27], fin[28],
      nullptr, h1, 0, 6144, 768, 768, 0, (long)3072*768, 3, 0, 0,
      1, 0, 0, 5120, 1.f, 1, 0, rows16, ofs16, cnt16);
  // expert down: A = h1 kblk-major (lda=5120), K=3072, ks=8 (per-m-tile grid)
  k_down<<<dim3(6,16,128), 256, 0, stream>>>(h1, fin[22], fin[22], fin[29], fin[29],
      nullptr, ye, 0, 768, 3072, 5120, 0, (long)768*3072, 3, 0, 768,
      1, 0, 0, 768, 1.f, 8, (long)5120*768, nullptr, ofs16, cnt16);
  // shared gate/up pair-interleaved -> kblk-major h1s (Mtot = 2560)
  k_sgup<<<dim3(24,16,2), 256, 0, stream>>>(x2c, fin[23], fin[24], fin[30], fin[31],
      nullptr, h1s, 0, 3072, 768, 768, 0, 0, 0, 0, 0,
      1, 0, 0, 2560, 1.f, 1, 0, nullptr, tabs+14, tabs+12);
  // shared down: A = h1s kblk-major (lda = 2560), K=1536, ks=2
  k_sdown<<<dim3(6,16,4), 256, 0, stream>>>(h1s, fin[25], fin[25], fin[32], fin[32],
      nullptr, ys, 0, 768, 1536, 2560, 0, 0, 0, 0, 768,
      1, 0, 0, 768, 1.f, 2, (long)2560*768, nullptr, tabs+14, tabs+12);

  combine_kernel<<<2048, 256, 0, stream>>>(h_i, mod_i, tkw_i, tpos_i,
      ye, (long)5120*768, ys, (long)2560*768, out_img, 1024);
  combine_kernel<<<512, 256, 0, stream>>>(h_t, mod_t, tkw_t, tpos_t,
      ye, (long)5120*768, ys + (long)2048*768, (long)2560*768, out_txt, 256);
}

// Round 18
// 948.702 us; speedup vs baseline: 1.1783x; 1.1211x over previous
//
#include <hip/hip_runtime.h>
#include <hip/hip_bf16.h>

using bf16 = __hip_bfloat16;
typedef __attribute__((ext_vector_type(4))) float f32x4;
typedef __attribute__((ext_vector_type(8))) short s16x8;

#define DEV static __device__ __forceinline__
DEV float bf2f(bf16 x){ return __bfloat162float(x); }
DEV bf16  f2bf(float x){ return __float2bfloat16(x); }
DEV float silu_(float x){ return x / (1.f + expf(-x)); }
// 16B-block XOR swizzle inside a 128x64 bf16 tile (row stride 64 elems = 8 blocks)
DEV int swz(int row, int colEl){ return row*64 + ((((colEl) >> 3) ^ (row & 7)) << 3); }
// same swizzle for a 16x64 tile
DEV int swz16(int row, int colEl){
  return row*64 + ((((colEl) >> 3) ^ (row & 7)) << 3) + ((colEl) & 7);
}

// ------------------------------------------------------------------
// Pipelined bf16 MFMA GEMM core (verified rounds 3-17).
// ------------------------------------------------------------------
template<bool B_F32, bool EXPERT, bool GATHER, int OUT, bool BIAS, bool PAIRB, bool ABLK>
DEV void gemm_core(
    const bf16* __restrict__ A,
    const void* __restrict__ B0a, const void* __restrict__ B0b,
    const void* __restrict__ B1a, const void* __restrict__ B1b,
    const float* __restrict__ bias, void* __restrict__ C,
    int M, int N, int K, int lda,
    long a_zoff, long b_zoff, int bshift, int biasz, int nsplitB,
    int zdiv, long c_so, long c_si, int ldc,
    float alpha, int ksplit, long c_spo,
    const int* __restrict__ rowlist, const int* __restrict__ offsets,
    const int* __restrict__ counts)
{
  __shared__ __align__(16) char smem_[32768];
  bf16* As = (bf16*)smem_;
  bf16* Bs = (bf16*)(smem_ + 16384);
  float (*st)[132] = (float(*)[132])smem_;

  const int zz = blockIdx.z;
  const int n0 = blockIdx.x * 128;
  const int z = zz / ksplit, split = zz % ksplit;
  int Meff = M; long rowbase = 0;
  if (EXPERT){ Meff = counts[z]; rowbase = offsets[z]; }
  const int m0 = blockIdx.y * 128;
  if (m0 >= Meff) return;
  const bf16* Ab = A + (EXPERT ? 0 : z * a_zoff);
  const int bidx = z >> bshift;
  const long e = (long)(z & ((1 << bshift) - 1));
  const void* BL = bidx ? B1a : B0a;
  const void* BU = bidx ? B1b : B0b;
  long coff;
  if (EXPERT) coff = rowbase * (long)ldc;
  else        coff = (long)(z / zdiv) * c_so + (long)(z % zdiv) * c_si;
  coff += (long)split * c_spo;
  const float* bias_eff = BIAS ? bias + (long)bidx * biasz : nullptr;

  const int klen = K / ksplit;
  const int kbeg = split * klen;
  const int NT = klen >> 6;

  const int tid = threadIdx.x;
  const int lane = tid & 63, wid = tid >> 6;
  const int wm = wid >> 1, wn = wid & 1;
  const int rbase = tid >> 3;
  const int kc = (tid & 7) << 3;

  const bf16* bp[4]; const float* bpf[4];
  bool bvalid[4];
  #pragma unroll
  for (int it = 0; it < 4; it++){
    int br = n0 + rbase + 32 * it;
    bvalid[it] = br < N;
    int brc = bvalid[it] ? br : 0;
    const void* Bsel; long brr;
    if (PAIRB){ Bsel = (brc & 1) ? BU : BL; brr = brc >> 1; }
    else { bool up = brc >= nsplitB; Bsel = up ? BU : BL; brr = up ? (brc - nsplitB) : brc; }
    if (B_F32) bpf[it] = (const float*)Bsel + e * b_zoff + brr * K + kbeg + kc;
    else       bp[it]  = (const bf16*) Bsel + e * b_zoff + brr * K + kbeg + kc;
  }
  const bf16* ap[4];
  bool avalid[4];
  #pragma unroll
  for (int it = 0; it < 4; it++){
    int row = rbase + 32 * it;
    long ar = 0;
    if (EXPERT){
      int i = m0 + row;
      avalid[it] = i < Meff;
      if (avalid[it]) ar = GATHER ? (long)rowlist[rowbase + i] : (rowbase + i);
    } else {
      avalid[it] = (m0 + row) < Meff;
      ar = m0 + row;
    }
    if (ABLK) ap[it] = Ab + ((long)(kbeg >> 6) * lda + ar) * 64 + kc;
    else      ap[it] = Ab + ar * (long)lda + kbeg + kc;
  }

  const uint4 zero4 = make_uint4(0u,0u,0u,0u);
  uint4 ra[4], rb[4];
  float4 fb0[4], fb1[4];

  auto LOAD = [&](int koff){
    long aoff = ABLK ? (long)koff * lda : (long)koff;
    #pragma unroll
    for (int it = 0; it < 4; it++){
      ra[it] = avalid[it] ? *(const uint4*)(ap[it] + aoff) : zero4;
      if (B_F32){
        if (bvalid[it]){ fb0[it] = *(const float4*)(bpf[it] + koff);
                         fb1[it] = *(const float4*)(bpf[it] + koff + 4); }
        else { fb0[it] = make_float4(0,0,0,0); fb1[it] = make_float4(0,0,0,0); }
      } else {
        rb[it] = bvalid[it] ? *(const uint4*)(bp[it] + koff) : zero4;
      }
    }
  };
  auto STORE = [&](){
    #pragma unroll
    for (int it = 0; it < 4; it++){
      int row = rbase + 32 * it;
      *(uint4*)(As + swz(row, kc)) = ra[it];
      if (B_F32){
        union { bf16 h[8]; uint4 v; } u;
        u.h[0]=f2bf(fb0[it].x); u.h[1]=f2bf(fb0[it].y); u.h[2]=f2bf(fb0[it].z); u.h[3]=f2bf(fb0[it].w);
        u.h[4]=f2bf(fb1[it].x); u.h[5]=f2bf(fb1[it].y); u.h[6]=f2bf(fb1[it].z); u.h[7]=f2bf(fb1[it].w);
        *(uint4*)(Bs + swz(row, kc)) = u.v;
      } else {
        *(uint4*)(Bs + swz(row, kc)) = rb[it];
      }
    }
  };

  f32x4 acc[4][4] = {};
  LOAD(0);
  for (int t = 0; t < NT; t++){
    STORE();
    __syncthreads();
    if (t + 1 < NT) LOAD((t + 1) << 6);
    #pragma unroll
    for (int ks2 = 0; ks2 < 2; ks2++){
      const int r16 = lane & 15;
      const int kk = ks2 * 32 + ((lane >> 4) << 3);
      s16x8 af[4], bfr[4];
      #pragma unroll
      for (int mi = 0; mi < 4; mi++) af[mi]  = *(const s16x8*)(As + swz(wm*64 + mi*16 + r16, kk));
      #pragma unroll
      for (int ni = 0; ni < 4; ni++) bfr[ni] = *(const s16x8*)(Bs + swz(wn*64 + ni*16 + r16, kk));
      #pragma unroll
      for (int mi = 0; mi < 4; mi++)
        #pragma unroll
        for (int ni = 0; ni < 4; ni++)
          acc[mi][ni] = __builtin_amdgcn_mfma_f32_16x16x32_bf16(af[mi], bfr[ni], acc[mi][ni], 0, 0, 0);
    }
    __syncthreads();
  }

  const int er = tid >> 3;
  const int ec = (tid & 7) << 4;
  const int erg = m0 + (er & 15) + ((er & 16) ? 64 : 0);
  #pragma unroll
  for (int mi = 0; mi < 4; mi++){
    #pragma unroll
    for (int ni = 0; ni < 4; ni++){
      int lc = wn*64 + ni*16 + (lane & 15);
      float bv = 0.f;
      if (BIAS){ if (split == 0) bv = bias_eff[n0 + lc]; }
      #pragma unroll
      for (int i = 0; i < 4; i++){
        int lr = wm*16 + ((lane >> 4) << 2) + i;
        st[lr][lc] = acc[mi][ni][i] * alpha + bv;
      }
    }
    __syncthreads();
    int rg = erg + mi*16;
    if (rg < Meff){
      if (OUT == 3){
        long base = ((long)(n0 >> 7) * (long)ldc + rowbase + rg) * 64 + (ec >> 1);
        union { bf16 h[8]; uint4 v; } o;
        #pragma unroll
        for (int j = 0; j < 8; j++)
          o.h[j] = f2bf(silu_(st[er][ec + 2*j]) * st[er][ec + 2*j + 1]);
        *(uint4*)((bf16*)C + base) = o.v;
      } else {
        int cg = n0 + ec;
        if (cg < N){
          long base = coff + (long)rg * ldc + cg;
          if (OUT == 0){
            float* dst = (float*)C + base;
            #pragma unroll
            for (int q = 0; q < 4; q++)
              *(float4*)(dst + 4*q) = make_float4(st[er][ec+4*q], st[er][ec+4*q+1],
                                                  st[er][ec+4*q+2], st[er][ec+4*q+3]);
          } else {
            union { bf16 h[8]; uint4 v; } o0, o1;
            #pragma unroll
            for (int j = 0; j < 8; j++){
              o0.h[j] = f2bf(st[er][ec+j]);
              o1.h[j] = f2bf(st[er][ec+8+j]);
            }
            *(uint4*)((bf16*)C + base)     = o0.v;
            *(uint4*)((bf16*)C + base + 8) = o1.v;
          }
        }
      }
    }
    __syncthreads();
  }
}

#define GEMM_K(NAME, BF32, EXPERT, GATHER, OUT, BIAS, PAIRB, ABLK)                 \
__global__ __launch_bounds__(256) void NAME(                                       \
    const bf16* A, const void* B0a, const void* B0b, const void* B1a,              \
    const void* B1b, const float* bias, void* C,                                   \
    int M, int N, int K, int lda, long az, long bz, int bshift, int biasz,         \
    int nsplitB, int zdiv, long cso, long csi, int ldc, float alpha, int ks,       \
    long cspo, const int* rl, const int* ofs, const int* cnt){                     \
  gemm_core<BF32,EXPERT,GATHER,OUT,BIAS,PAIRB,ABLK>(A,B0a,B0b,B1a,B1b,bias,C,      \
      M,N,K,lda,az,bz,bshift,biasz,nsplitB,zdiv,cso,csi,ldc,alpha,ks,cspo,rl,ofs,cnt); }

GEMM_K(k_qkv,  true ,true ,false,1,true ,false,false)
GEMM_K(k_proj, true ,true ,false,0,true ,false,false)
GEMM_K(k_gup,  true ,true ,true ,3,false,true ,false)
GEMM_K(k_down, true ,true ,false,1,false,false,true )
GEMM_K(k_sgup, true ,true ,false,3,false,true ,false)
GEMM_K(k_sdown,true ,true ,false,0,false,false,true )

// ------------------------------------------------------------------
// Flash attention: one block = 64 q-rows x 1 head; wave = 16 q-rows.
// Q,K: [bh][seq][64] bf16 (RMS-normed); Vt: [bh][64][1280] bf16.
// Online softmax (running m,l per q-row); zero barriers (per-wave LDS).
// O out: [b][row][hh*64+d] bf16.
// ------------------------------------------------------------------
__global__ __launch_bounds__(256) void k_flash(
    const bf16* __restrict__ Q, const bf16* __restrict__ Kb,
    const bf16* __restrict__ Vt, bf16* __restrict__ O)
{
  __shared__ __align__(16) bf16 plds[4][16*64];
  const int bh = blockIdx.y;
  const int b = bh / 12, hh = bh % 12;
  const int tid = threadIdx.x;
  const int wid = tid >> 6, lane = tid & 63;
  const int q0 = blockIdx.x * 64 + wid * 16;
  const int r = lane & 15, g = lane >> 4;
  const long qbase = (long)bh * 1280 * 64;
  const long vbase = (long)bh * 64 * 1280;
  bf16* pw = plds[wid];

  s16x8 qa0 = *(const s16x8*)(Q + qbase + (long)(q0 + r) * 64 + g*8);
  s16x8 qa1 = *(const s16x8*)(Q + qbase + (long)(q0 + r) * 64 + 32 + g*8);

  f32x4 oacc[4] = {};
  float m_[4] = {-1e30f,-1e30f,-1e30f,-1e30f};
  float l_[4] = {0.f,0.f,0.f,0.f};

  for (int kt = 0; kt < 20; kt++){
    const int kv0 = kt * 64;
    // ---- S = 0.125 * Q @ K^T (4 frags of 16 kv cols) ----
    f32x4 sf[4];
    #pragma unroll
    for (int nf = 0; nf < 4; nf++){
      const bf16* kr = Kb + qbase + (long)(kv0 + nf*16 + r) * 64;
      s16x8 kb0 = *(const s16x8*)(kr + g*8);
      s16x8 kb1 = *(const s16x8*)(kr + 32 + g*8);
      f32x4 s = {};
      s = __builtin_amdgcn_mfma_f32_16x16x32_bf16(qa0, kb0, s, 0, 0, 0);
      s = __builtin_amdgcn_mfma_f32_16x16x32_bf16(qa1, kb1, s, 0, 0, 0);
      #pragma unroll
      for (int i = 0; i < 4; i++) s[i] *= 0.125f;
      sf[nf] = s;
    }
    // ---- row max over 64 cols: local over nf, then 16-lane xor-reduce ----
    float pm[4];
    #pragma unroll
    for (int i = 0; i < 4; i++)
      pm[i] = fmaxf(fmaxf(sf[0][i], sf[1][i]), fmaxf(sf[2][i], sf[3][i]));
    #pragma unroll
    for (int o = 1; o <= 8; o <<= 1)
      #pragma unroll
      for (int i = 0; i < 4; i++) pm[i] = fmaxf(pm[i], __shfl_xor(pm[i], o));
    float mn[4], al[4];
    #pragma unroll
    for (int i = 0; i < 4; i++){
      mn[i] = fmaxf(m_[i], pm[i]);
      al[i] = __expf(m_[i] - mn[i]);
    }
    // ---- P = exp(S - mn), row sum ----
    float rs_[4] = {0.f,0.f,0.f,0.f};
    #pragma unroll
    for (int nf = 0; nf < 4; nf++)
      #pragma unroll
      for (int i = 0; i < 4; i++){
        float p = __expf(sf[nf][i] - mn[i]);
        sf[nf][i] = p;
        rs_[i] += p;
      }
    #pragma unroll
    for (int o = 1; o <= 8; o <<= 1)
      #pragma unroll
      for (int i = 0; i < 4; i++) rs_[i] += __shfl_xor(rs_[i], o);
    #pragma unroll
    for (int i = 0; i < 4; i++){
      l_[i] = l_[i] * al[i] + rs_[i];
      m_[i] = mn[i];
    }
    // ---- rescale O accumulator ----
    #pragma unroll
    for (int nf = 0; nf < 4; nf++)
      #pragma unroll
      for (int i = 0; i < 4; i++) oacc[nf][i] *= al[i];
    // ---- P -> per-wave LDS (C-layout -> A-layout transpose), swizzled ----
    #pragma unroll
    for (int nf = 0; nf < 4; nf++)
      #pragma unroll
      for (int i = 0; i < 4; i++)
        pw[swz16(g*4 + i, nf*16 + r)] = f2bf(sf[nf][i]);
    // wave-synchronous: same-wave ds_write -> ds_read, compiler inserts waits
    s16x8 pa0 = *(const s16x8*)(pw + swz16(r, g*8));
    s16x8 pa1 = *(const s16x8*)(pw + swz16(r, 32 + g*8));
    // ---- O += P @ V  (Vt rows = d, contiguous kv) ----
    #pragma unroll
    for (int nf = 0; nf < 4; nf++){
      const bf16* vr = Vt + vbase + (long)(nf*16 + r) * 1280 + kv0;
      s16x8 vb0 = *(const s16x8*)(vr + g*8);
      s16x8 vb1 = *(const s16x8*)(vr + 32 + g*8);
      oacc[nf] = __builtin_amdgcn_mfma_f32_16x16x32_bf16(pa0, vb0, oacc[nf], 0, 0, 0);
      oacc[nf] = __builtin_amdgcn_mfma_f32_16x16x32_bf16(pa1, vb1, oacc[nf], 0, 0, 0);
    }
  }
  // ---- finalize: O /= l, store bf16 ----
  #pragma unroll
  for (int i = 0; i < 4; i++){
    float inv = 1.f / l_[i];
    int row = q0 + g*4 + i;
    #pragma unroll
    for (int nf = 0; nf < 4; nf++)
      O[((long)b*1280 + row)*768 + hh*64 + nf*16 + r] = f2bf(oacc[nf][i] * inv);
  }
}

// ---- init / tables ----
__global__ void init_kernel(int* cnt16, int* tabs){
  int i = threadIdx.x;
  if (i < 16) cnt16[i] = 0;
  if (i == 0){
    tabs[0]=2048; tabs[1]=512; tabs[2]=0; tabs[3]=2048;          // qkv cnt/ofs
    tabs[4]=256; tabs[5]=256; tabs[6]=1024; tabs[7]=1024;        // proj cnt
    tabs[8]=0; tabs[9]=1280; tabs[10]=256; tabs[11]=1536;        // proj ofs
    tabs[12]=2048; tabs[13]=512; tabs[14]=0; tabs[15]=2048;      // shared cnt/ofs
  }
}
__global__ void tables_kernel(const int* cnt16, int* ofs16, int* cur16){
  if (threadIdx.x == 0){
    int o = 0;
    for (int e = 0; e < 8; e++){ ofs16[e] = o; o += cnt16[e]; cur16[e] = 0; }
    o = 4096;
    for (int e = 8; e < 16; e++){ ofs16[e] = o; o += cnt16[e]; cur16[e] = 0; }
  }
}

// ---- modulation GEMV ----
__global__ __launch_bounds__(256) void mod_kernel(const float* __restrict__ vec,
    const float* __restrict__ w, const float* __restrict__ b, float* __restrict__ out){
  int bb = blockIdx.y;
  __shared__ float sv[768];
  int tid = threadIdx.x;
  for (int i = tid; i < 768; i += 256){ float v = vec[bb*768 + i]; sv[i] = v/(1.f+expf(-v)); }
  __syncthreads();
  int w4 = tid >> 6, lane = tid & 63;
  int j0 = blockIdx.x * 8 + w4 * 2;
  for (int jj = 0; jj < 2; jj++){
    int j = j0 + jj;
    const float* wr = w + (long)j * 768;
    float p = 0.f;
    #pragma unroll
    for (int i = 0; i < 12; i++) p += sv[lane + 64*i] * wr[lane + 64*i];
    for (int o = 32; o; o >>= 1) p += __shfl_xor(p, o);
    if (lane == 0) out[bb*4608 + j] = p + b[j];
  }
}

// ---- y = (1+c)*LN(x) + s ----
__global__ __launch_bounds__(256) void ln_mod_kernel(const float* __restrict__ x,
    const float* __restrict__ mod, bf16* __restrict__ y, int L){
  int t = blockIdx.x; int b = t / L;
  const float* xr = x + (long)t * 768;
  __shared__ float red[256];
  int tid = threadIdx.x;
  float v[3]; float s = 0.f;
  #pragma unroll
  for (int i = 0; i < 3; i++){ v[i] = xr[tid + 256*i]; s += v[i]; }
  red[tid] = s; __syncthreads();
  for (int o = 128; o; o >>= 1){ if (tid < o) red[tid] += red[tid+o]; __syncthreads(); }
  float mean = red[0] * (1.f/768.f); __syncthreads();
  float s2 = 0.f;
  #pragma unroll
  for (int i = 0; i < 3; i++){ float d = v[i]-mean; s2 += d*d; }
  red[tid] = s2; __syncthreads();
  for (int o = 128; o; o >>= 1){ if (tid < o) red[tid] += red[tid+o]; __syncthreads(); }
  float rs = rsqrtf(red[0] * (1.f/768.f) + 1e-6f);
  const float* mb = mod + (long)b * 4608;
  #pragma unroll
  for (int i = 0; i < 3; i++){
    int d = tid + 256*i;
    y[(long)t*768 + d] = f2bf((1.f + mb[768+d]) * ((v[i]-mean)*rs) + mb[d]);
  }
}

// ---- h = x + g1*(pjA+pjB) ; y = (1+c2)*LN(h) + s2 ----
__global__ __launch_bounds__(256) void resid_ln_mod_kernel(const float* __restrict__ x,
    const float* __restrict__ pj, int pjoff, long pjspo, const float* __restrict__ mod,
    float* __restrict__ h, bf16* __restrict__ y, float* __restrict__ yf, int L){
  int t = blockIdx.x; int b = t / L;
  const float* mb = mod + (long)b * 4608;
  const float* xr = x + (long)t * 768;
  long pr = (long)(pjoff + b*1280 + (t % L)) * 768;
  __shared__ float red[256];
  int tid = threadIdx.x;
  float v[3]; float s = 0.f;
  #pragma unroll
  for (int i = 0; i < 3; i++){
    int d = tid + 256*i;
    float pv = pj[pr + d] + pj[pjspo + pr + d];
    float hv = xr[d] + mb[2*768 + d] * pv;
    h[(long)t*768 + d] = hv;
    v[i] = hv; s += hv;
  }
  red[tid] = s; __syncthreads();
  for (int o = 128; o; o >>= 1){ if (tid < o) red[tid] += red[tid+o]; __syncthreads(); }
  float mean = red[0] * (1.f/768.f); __syncthreads();
  float s2 = 0.f;
  #pragma unroll
  for (int i = 0; i < 3; i++){ float d = v[i]-mean; s2 += d*d; }
  red[tid] = s2; __syncthreads();
  for (int o = 128; o; o >>= 1){ if (tid < o) red[tid] += red[tid+o]; __syncthreads(); }
  float rs = rsqrtf(red[0] * (1.f/768.f) + 1e-6f);
  #pragma unroll
  for (int i = 0; i < 3; i++){
    int d = tid + 256*i;
    float val = (1.f + mb[4*768+d]) * ((v[i]-mean)*rs) + mb[3*768+d];
    y[(long)t*768 + d] = f2bf(val);
    yf[(long)t*768 + d] = val;
  }
}

// ---- qkv rows -> RMS-normed Q,K + transposed V ----
__global__ __launch_bounds__(256) void qkv_scatter_kernel(const bf16* __restrict__ qkv,
    const float* __restrict__ qs, const float* __restrict__ ks,
    bf16* __restrict__ Q, bf16* __restrict__ Kb, bf16* __restrict__ Vt,
    int L, int seqoff){
  __shared__ float vt[64][65];
  int bh = blockIdx.y;
  int b = bh / 12, hh = bh % 12;
  int st = blockIdx.x * 64;
  int w = threadIdx.x >> 6, lane = threadIdx.x & 63;
  float qsc = qs[lane], ksc = ks[lane];
  long qkvbase = (long)b * L * 2304;
  long outbase = (long)bh * 1280 * 64;
  #pragma unroll 4
  for (int i = 0; i < 16; i++){
    int r = w*16 + i;
    int t = st + r;
    const bf16* row = qkv + qkvbase + (long)t * 2304;
    float q = bf2f(row[hh*64 + lane]);
    float k = bf2f(row[768 + hh*64 + lane]);
    float v = bf2f(row[1536 + hh*64 + lane]);
    float q2 = q*q, k2 = k*k;
    for (int o = 32; o; o >>= 1){ q2 += __shfl_xor(q2, o); k2 += __shfl_xor(k2, o); }
    q = q * rsqrtf(q2*(1.f/64.f) + 1e-6f) * qsc;
    k = k * rsqrtf(k2*(1.f/64.f) + 1e-6f) * ksc;
    int seq = seqoff + t;
    Q [outbase + (long)seq*64 + lane] = f2bf(q);
    Kb[outbase + (long)seq*64 + lane] = f2bf(k);
    vt[r][lane] = v;
  }
  __syncthreads();
  #pragma unroll 4
  for (int i = 0; i < 16; i++){
    int d = w*16 + i;
    Vt[outbase + (long)d*1280 + seqoff + st + lane] = f2bf(vt[lane][d]);
  }
}

// ---- router ----
__global__ __launch_bounds__(256) void router_kernel(const float* __restrict__ x2,
    const float* __restrict__ gw, float* __restrict__ tkw, int* __restrict__ tki,
    int* __restrict__ counts, int T){
  int t = blockIdx.x * 4 + (threadIdx.x >> 6);
  int lane = threadIdx.x & 63;
  if (t >= T) return;
  const float* xr = x2 + (long)t * 768;
  float xs[12];
  #pragma unroll
  for (int i = 0; i < 12; i++) xs[i] = xr[lane + 64*i];
  float sc[8];
  #pragma unroll
  for (int e = 0; e < 8; e++){
    const float* gr = gw + e * 768;
    float p = 0.f;
    #pragma unroll
    for (int i = 0; i < 12; i++) p += xs[i] * gr[lane + 64*i];
    for (int o = 32; o; o >>= 1) p += __shfl_xor(p, o);
    sc[e] = p;
  }
  if (lane == 0){
    float m = sc[0];
    for (int e = 1; e < 8; e++) m = fmaxf(m, sc[e]);
    float s = 0.f;
    for (int e = 0; e < 8; e++){ sc[e] = expf(sc[e] - m); s += sc[e]; }
    float inv = 1.f / s;
    for (int e = 0; e < 8; e++) sc[e] *= inv;
    int i0 = 0;
    for (int e = 1; e < 8; e++) if (sc[e] > sc[i0]) i0 = e;
    int i1 = -1;
    for (int e = 0; e < 8; e++){ if (e == i0) continue; if (i1 < 0 || sc[e] > sc[i1]) i1 = e; }
    tkw[t*2] = sc[i0]; tkw[t*2+1] = sc[i1];
    tki[t*2] = i0;     tki[t*2+1] = i1;
    atomicAdd(&counts[i0], 1); atomicAdd(&counts[i1], 1);
  }
}

__global__ __launch_bounds__(256) void scatter_kernel(const int* __restrict__ tki,
    const int* __restrict__ ofs16, int* __restrict__ cur16,
    int* __restrict__ rows16, int* __restrict__ tpos, int T, int tabofs, int rowadd){
  int idx = blockIdx.x * 256 + threadIdx.x;
  if (idx >= T * 2) return;
  int t = idx >> 1;
  int e = tki[idx];
  int pos = atomicAdd(&cur16[tabofs + e], 1);
  int g = ofs16[tabofs + e] + pos;
  rows16[g] = rowadd + t;
  tpos[idx] = g;
}

// ---- out = h + g2 * (w0*sum8(ye_bf16)[p0] + w1*sum8(ye_bf16)[p1] + sum2(ys)) ----
__global__ __launch_bounds__(256) void combine_kernel(const float* __restrict__ h,
    const float* __restrict__ mod, const float* __restrict__ tkw, const int* __restrict__ tpos,
    const bf16* __restrict__ ye, long espo, const float* __restrict__ ys, long sspo,
    float* __restrict__ out, int L){
  int t = blockIdx.x; int b = t / L;
  const float* g2 = mod + (long)b * 4608 + 5*768;
  float w0 = tkw[t*2], w1 = tkw[t*2+1];
  long p0 = (long)tpos[t*2] * 768, p1 = (long)tpos[t*2+1] * 768;
  for (int d = threadIdx.x; d < 768; d += 256){
    float e0 = 0.f, e1 = 0.f, sv = 0.f;
    #pragma unroll
    for (int sp = 0; sp < 8; sp++){
      e0 += bf2f(ye[sp*espo + p0 + d]);
      e1 += bf2f(ye[sp*espo + p1 + d]);
    }
    #pragma unroll
    for (int sp = 0; sp < 2; sp++) sv += ys[sp*sspo + (long)t*768 + d];
    out[(long)t*768 + d] = h[(long)t*768 + d] + g2[d] * (w0*e0 + w1*e1 + sv);
  }
}

// =================================================================================
extern "C" void kernel_launch(void* const* d_in, const int* in_sizes, int n_in,
                              void* d_out, int out_size, void* d_ws, size_t ws_size,
                              hipStream_t stream){
  (void)in_sizes; (void)n_in; (void)out_size; (void)ws_size;
  const float* fin[33];
  for (int i = 0; i < 33; i++) fin[i] = (const float*)d_in[i];
  float* out_img = (float*)d_out;
  float* out_txt = (float*)d_out + (long)2*1024*768;

  char* ws = (char*)d_ws;
  size_t off = 0;
  auto alloc = [&](size_t n)->char*{
    off = (off + 255) & ~(size_t)255;
    char* p = ws + off; off += n; return p;
  };

  // ---- persistent ----
  float* mod_i=(float*)alloc(2*4608*4);
  float* mod_t=(float*)alloc(2*4608*4);
  float* h_i  =(float*)alloc((size_t)2048*768*4);
  float* h_t  =(float*)alloc((size_t)512*768*4);
  bf16*  x2c  =(bf16*) alloc((size_t)2560*768*2);
  float* x2fc =(float*)alloc((size_t)2560*768*4);
  float* tkw_i=(float*)alloc(2048*2*4);
  int*   tki_i=(int*)  alloc(2048*2*4);
  float* tkw_t=(float*)alloc(512*2*4);
  int*   tki_t=(int*)  alloc(512*2*4);
  int* cnt16=(int*)alloc(16*4);
  int* ofs16=(int*)alloc(16*4);
  int* cur16=(int*)alloc(16*4);
  int* rows16=(int*)alloc(5120*4);
  int* tpos_i=(int*)alloc(4096*4);
  int* tpos_t=(int*)alloc(1024*4);
  int* tabs=(int*)alloc(64*4);
  float* qb_ws=(float*)alloc(2*2304*4);
  float* pb_ws=(float*)alloc(2*768*4);

  size_t arena = (off + 255) & ~(size_t)255;
  // ---- phase A ----
  off = arena;
  bf16* Qb=(bf16*)alloc((size_t)24*1280*64*2);
  bf16* Kb=(bf16*)alloc((size_t)24*1280*64*2);
  bf16* Vt=(bf16*)alloc((size_t)24*1280*64*2);
  bf16* O =(bf16*)alloc((size_t)2*1280*768*2);
  float* pjc=(float*)alloc((size_t)2*2560*768*4);
  bf16* xmc=(bf16*)alloc((size_t)2560*768*2);
  bf16* qrc=(bf16*)alloc((size_t)2560*2304*2);
  // ---- phase B (overlays phase A) ----
  off = arena;
  bf16*  h1 =(bf16*) alloc((size_t)48*5120*64*2);    // kblk-major silu(g)*u
  bf16*  ye =(bf16*) alloc((size_t)8*5120*768*2);    // 8 k-split partials (bf16)
  bf16*  h1s=(bf16*) alloc((size_t)24*2560*64*2);    // kblk-major shared
  float* ys =(float*)alloc((size_t)2*2560*768*4);

  // bias concat copies (tiny)
  hipMemcpyAsync(qb_ws,      fin[8],  2304*4, hipMemcpyDeviceToDevice, stream);
  hipMemcpyAsync(qb_ws+2304, fin[12], 2304*4, hipMemcpyDeviceToDevice, stream);
  hipMemcpyAsync(pb_ws,      fin[14], 768*4,  hipMemcpyDeviceToDevice, stream);
  hipMemcpyAsync(pb_ws+768,  fin[10], 768*4,  hipMemcpyDeviceToDevice, stream);

  init_kernel<<<1, 64, 0, stream>>>(cnt16, tabs);
  mod_kernel<<<dim3(576,2), 256, 0, stream>>>(fin[2], fin[3], fin[4], mod_i);
  mod_kernel<<<dim3(576,2), 256, 0, stream>>>(fin[2], fin[5], fin[6], mod_t);
  ln_mod_kernel<<<2048, 256, 0, stream>>>(fin[0], mod_i, xmc, 1024);
  ln_mod_kernel<<<512,  256, 0, stream>>>(fin[1], mod_t, xmc + (long)2048*768, 256);

  // QKV: z=2 (img table 0, txt table 1); f32 B
  k_qkv<<<dim3(18,16,2), 256, 0, stream>>>(xmc, fin[7], fin[7], fin[11], fin[11],
      qb_ws, qrc, 0, 2304, 768, 768, 0, 0, 0, 2304, 2304,
      1, 0, 0, 2304, 1.f, 1, 0, nullptr, tabs+2, tabs+0);
  qkv_scatter_kernel<<<dim3(16,24), 256, 0, stream>>>(qrc, fin[15], fin[16], Qb, Kb, Vt, 1024, 256);
  qkv_scatter_kernel<<<dim3(4,24),  256, 0, stream>>>(qrc + (long)2048*2304, fin[17], fin[18], Qb, Kb, Vt, 256, 0);

  // flash attention: replaces qkt/softmax/pv/reduce (no S/Opart materialization)
  k_flash<<<dim3(20,24), 256, 0, stream>>>(Qb, Kb, Vt, O);

  // proj: z=4 tables, bidx=z>>1, ks=2 (f32 B)
  k_proj<<<dim3(6,8,8), 256, 0, stream>>>(O, fin[13], fin[13], fin[9], fin[9],
      pb_ws, pjc, 0, 768, 768, 768, 0, 0, 1, 768, 768,
      1, 0, 0, 768, 1.f, 2, (long)2560*768, nullptr, tabs+8, tabs+4);
  resid_ln_mod_kernel<<<2048, 256, 0, stream>>>(fin[0], pjc, 256, (long)2560*768,
      mod_i, h_i, x2c, x2fc, 1024);
  resid_ln_mod_kernel<<<512, 256, 0, stream>>>(fin[1], pjc, 0, (long)2560*768,
      mod_t, h_t, x2c + (long)2048*768, x2fc + (long)2048*768, 256);

  router_kernel<<<512, 256, 0, stream>>>(x2fc, fin[19], tkw_i, tki_i, cnt16, 2048);
  router_kernel<<<128, 256, 0, stream>>>(x2fc + (long)2048*768, fin[26], tkw_t, tki_t, cnt16+8, 512);
  tables_kernel<<<1, 1, 0, stream>>>(cnt16, ofs16, cur16);
  scatter_kernel<<<16, 256, 0, stream>>>(tki_i, ofs16, cur16, rows16, tpos_i, 2048, 0, 0);
  scatter_kernel<<<4,  256, 0, stream>>>(tki_t, ofs16, cur16, rows16, tpos_t, 512, 8, 2048);

  // expert gate/up pair-interleaved -> kblk-major h1 (per-m-tile grid, early exit)
  k_gup<<<dim3(48,16,16), 256, 0, stream>>>(x2c, fin[20], fin[21], fin[27], fin[28],
      nullptr, h1, 0, 6144, 768, 768, 0, (long)3072*768, 3, 0, 0,
      1, 0, 0, 5120, 1.f, 1, 0, rows16, ofs16, cnt16);
  // expert down: A = h1 kblk-major (lda=5120), K=3072, ks=8 (per-m-tile grid)
  k_down<<<dim3(6,16,128), 256, 0, stream>>>(h1, fin[22], fin[22], fin[29], fin[29],
      nullptr, ye, 0, 768, 3072, 5120, 0, (long)768*3072, 3, 0, 768,
      1, 0, 0, 768, 1.f, 8, (long)5120*768, nullptr, ofs16, cnt16);
  // shared gate/up pair-interleaved -> kblk-major h1s (Mtot = 2560)
  k_sgup<<<dim3(24,16,2), 256, 0, stream>>>(x2c, fin[23], fin[24], fin[30], fin[31],
      nullptr, h1s, 0, 3072, 768, 768, 0, 0, 0, 0, 0,
      1, 0, 0, 2560, 1.f, 1, 0, nullptr, tabs+14, tabs+12);
  // shared down: A = h1s kblk-major (lda = 2560), K=1536, ks=2
  k_sdown<<<dim3(6,16,4), 256, 0, stream>>>(h1s, fin[25], fin[25], fin[32], fin[32],
      nullptr, ys, 0, 768, 1536, 2560, 0, 0, 0, 0, 768,
      1, 0, 0, 768, 1.f, 2, (long)2560*768, nullptr, tabs+14, tabs+12);

  combine_kernel<<<2048, 256, 0, stream>>>(h_i, mod_i, tkw_i, tpos_i,
      ye, (long)5120*768, ys, (long)2560*768, out_img, 1024);
  combine_kernel<<<512, 256, 0, stream>>>(h_t, mod_t, tkw_t, tpos_t,
      ye, (long)5120*768, ys + (long)2048*768, (long)2560*768, out_txt, 256);
}

// Round 20
// 938.530 us; speedup vs baseline: 1.1911x; 1.0108x over previous
//
#include <hip/hip_runtime.h>
#include <hip/hip_bf16.h>

using bf16 = __hip_bfloat16;
typedef __attribute__((ext_vector_type(4))) float f32x4;
typedef __attribute__((ext_vector_type(8))) short s16x8;

#define DEV static __device__ __forceinline__
DEV float bf2f(bf16 x){ return __bfloat162float(x); }
DEV bf16  f2bf(float x){ return __float2bfloat16(x); }
DEV float silu_(float x){ return x / (1.f + expf(-x)); }
// 16B-block XOR swizzle inside a 128x64 bf16 tile (row stride 64 elems = 8 blocks)
DEV int swz(int row, int colEl){ return row*64 + ((((colEl) >> 3) ^ (row & 7)) << 3); }
// same swizzle for a 16x64 tile
DEV int swz16(int row, int colEl){
  return row*64 + ((((colEl) >> 3) ^ (row & 7)) << 3) + ((colEl) & 7);
}

// ------------------------------------------------------------------
// Pipelined bf16 MFMA GEMM core (verified rounds 3-18).
// ------------------------------------------------------------------
template<bool B_F32, bool EXPERT, bool GATHER, int OUT, bool BIAS, bool PAIRB, bool ABLK>
DEV void gemm_core(
    const bf16* __restrict__ A,
    const void* __restrict__ B0a, const void* __restrict__ B0b,
    const void* __restrict__ B1a, const void* __restrict__ B1b,
    const float* __restrict__ bias, void* __restrict__ C,
    int M, int N, int K, int lda,
    long a_zoff, long b_zoff, int bshift, int biasz, int nsplitB,
    int zdiv, long c_so, long c_si, int ldc,
    float alpha, int ksplit, long c_spo,
    const int* __restrict__ rowlist, const int* __restrict__ offsets,
    const int* __restrict__ counts)
{
  __shared__ __align__(16) char smem_[32768];
  bf16* As = (bf16*)smem_;
  bf16* Bs = (bf16*)(smem_ + 16384);
  float (*st)[132] = (float(*)[132])smem_;

  const int zz = blockIdx.z;
  const int n0 = blockIdx.x * 128;
  const int z = zz / ksplit, split = zz % ksplit;
  int Meff = M; long rowbase = 0;
  if (EXPERT){ Meff = counts[z]; rowbase = offsets[z]; }
  const int m0 = blockIdx.y * 128;
  if (m0 >= Meff) return;
  const bf16* Ab = A + (EXPERT ? 0 : z * a_zoff);
  const int bidx = z >> bshift;
  const long e = (long)(z & ((1 << bshift) - 1));
  const void* BL = bidx ? B1a : B0a;
  const void* BU = bidx ? B1b : B0b;
  long coff;
  if (EXPERT) coff = rowbase * (long)ldc;
  else        coff = (long)(z / zdiv) * c_so + (long)(z % zdiv) * c_si;
  coff += (long)split * c_spo;
  const float* bias_eff = BIAS ? bias + (long)bidx * biasz : nullptr;

  const int klen = K / ksplit;
  const int kbeg = split * klen;
  const int NT = klen >> 6;

  const int tid = threadIdx.x;
  const int lane = tid & 63, wid = tid >> 6;
  const int wm = wid >> 1, wn = wid & 1;
  const int rbase = tid >> 3;
  const int kc = (tid & 7) << 3;

  const bf16* bp[4]; const float* bpf[4];
  bool bvalid[4];
  #pragma unroll
  for (int it = 0; it < 4; it++){
    int br = n0 + rbase + 32 * it;
    bvalid[it] = br < N;
    int brc = bvalid[it] ? br : 0;
    const void* Bsel; long brr;
    if (PAIRB){ Bsel = (brc & 1) ? BU : BL; brr = brc >> 1; }
    else { bool up = brc >= nsplitB; Bsel = up ? BU : BL; brr = up ? (brc - nsplitB) : brc; }
    if (B_F32) bpf[it] = (const float*)Bsel + e * b_zoff + brr * K + kbeg + kc;
    else       bp[it]  = (const bf16*) Bsel + e * b_zoff + brr * K + kbeg + kc;
  }
  const bf16* ap[4];
  bool avalid[4];
  #pragma unroll
  for (int it = 0; it < 4; it++){
    int row = rbase + 32 * it;
    long ar = 0;
    if (EXPERT){
      int i = m0 + row;
      avalid[it] = i < Meff;
      if (avalid[it]) ar = GATHER ? (long)rowlist[rowbase + i] : (rowbase + i);
    } else {
      avalid[it] = (m0 + row) < Meff;
      ar = m0 + row;
    }
    if (ABLK) ap[it] = Ab + ((long)(kbeg >> 6) * lda + ar) * 64 + kc;
    else      ap[it] = Ab + ar * (long)lda + kbeg + kc;
  }

  const uint4 zero4 = make_uint4(0u,0u,0u,0u);
  uint4 ra[4], rb[4];
  float4 fb0[4], fb1[4];

  auto LOAD = [&](int koff){
    long aoff = ABLK ? (long)koff * lda : (long)koff;
    #pragma unroll
    for (int it = 0; it < 4; it++){
      ra[it] = avalid[it] ? *(const uint4*)(ap[it] + aoff) : zero4;
      if (B_F32){
        if (bvalid[it]){ fb0[it] = *(const float4*)(bpf[it] + koff);
                         fb1[it] = *(const float4*)(bpf[it] + koff + 4); }
        else { fb0[it] = make_float4(0,0,0,0); fb1[it] = make_float4(0,0,0,0); }
      } else {
        rb[it] = bvalid[it] ? *(const uint4*)(bp[it] + koff) : zero4;
      }
    }
  };
  auto STORE = [&](){
    #pragma unroll
    for (int it = 0; it < 4; it++){
      int row = rbase + 32 * it;
      *(uint4*)(As + swz(row, kc)) = ra[it];
      if (B_F32){
        union { bf16 h[8]; uint4 v; } u;
        u.h[0]=f2bf(fb0[it].x); u.h[1]=f2bf(fb0[it].y); u.h[2]=f2bf(fb0[it].z); u.h[3]=f2bf(fb0[it].w);
        u.h[4]=f2bf(fb1[it].x); u.h[5]=f2bf(fb1[it].y); u.h[6]=f2bf(fb1[it].z); u.h[7]=f2bf(fb1[it].w);
        *(uint4*)(Bs + swz(row, kc)) = u.v;
      } else {
        *(uint4*)(Bs + swz(row, kc)) = rb[it];
      }
    }
  };

  f32x4 acc[4][4] = {};
  LOAD(0);
  for (int t = 0; t < NT; t++){
    STORE();
    __syncthreads();
    if (t + 1 < NT) LOAD((t + 1) << 6);
    #pragma unroll
    for (int ks2 = 0; ks2 < 2; ks2++){
      const int r16 = lane & 15;
      const int kk = ks2 * 32 + ((lane >> 4) << 3);
      s16x8 af[4], bfr[4];
      #pragma unroll
      for (int mi = 0; mi < 4; mi++) af[mi]  = *(const s16x8*)(As + swz(wm*64 + mi*16 + r16, kk));
      #pragma unroll
      for (int ni = 0; ni < 4; ni++) bfr[ni] = *(const s16x8*)(Bs + swz(wn*64 + ni*16 + r16, kk));
      #pragma unroll
      for (int mi = 0; mi < 4; mi++)
        #pragma unroll
        for (int ni = 0; ni < 4; ni++)
          acc[mi][ni] = __builtin_amdgcn_mfma_f32_16x16x32_bf16(af[mi], bfr[ni], acc[mi][ni], 0, 0, 0);
    }
    __syncthreads();
  }

  const int er = tid >> 3;
  const int ec = (tid & 7) << 4;
  const int erg = m0 + (er & 15) + ((er & 16) ? 64 : 0);
  #pragma unroll
  for (int mi = 0; mi < 4; mi++){
    #pragma unroll
    for (int ni = 0; ni < 4; ni++){
      int lc = wn*64 + ni*16 + (lane & 15);
      float bv = 0.f;
      if (BIAS){ if (split == 0) bv = bias_eff[n0 + lc]; }
      #pragma unroll
      for (int i = 0; i < 4; i++){
        int lr = wm*16 + ((lane >> 4) << 2) + i;
        st[lr][lc] = acc[mi][ni][i] * alpha + bv;
      }
    }
    __syncthreads();
    int rg = erg + mi*16;
    if (rg < Meff){
      if (OUT == 3){
        long base = ((long)(n0 >> 7) * (long)ldc + rowbase + rg) * 64 + (ec >> 1);
        union { bf16 h[8]; uint4 v; } o;
        #pragma unroll
        for (int j = 0; j < 8; j++)
          o.h[j] = f2bf(silu_(st[er][ec + 2*j]) * st[er][ec + 2*j + 1]);
        *(uint4*)((bf16*)C + base) = o.v;
      } else {
        int cg = n0 + ec;
        if (cg < N){
          long base = coff + (long)rg * ldc + cg;
          if (OUT == 0){
            float* dst = (float*)C + base;
            #pragma unroll
            for (int q = 0; q < 4; q++)
              *(float4*)(dst + 4*q) = make_float4(st[er][ec+4*q], st[er][ec+4*q+1],
                                                  st[er][ec+4*q+2], st[er][ec+4*q+3]);
          } else {
            union { bf16 h[8]; uint4 v; } o0, o1;
            #pragma unroll
            for (int j = 0; j < 8; j++){
              o0.h[j] = f2bf(st[er][ec+j]);
              o1.h[j] = f2bf(st[er][ec+8+j]);
            }
            *(uint4*)((bf16*)C + base)     = o0.v;
            *(uint4*)((bf16*)C + base + 8) = o1.v;
          }
        }
      }
    }
    __syncthreads();
  }
}

#define GEMM_K(NAME, BF32, EXPERT, GATHER, OUT, BIAS, PAIRB, ABLK)                 \
__global__ __launch_bounds__(256) void NAME(                                       \
    const bf16* A, const void* B0a, const void* B0b, const void* B1a,              \
    const void* B1b, const float* bias, void* C,                                   \
    int M, int N, int K, int lda, long az, long bz, int bshift, int biasz,         \
    int nsplitB, int zdiv, long cso, long csi, int ldc, float alpha, int ks,       \
    long cspo, const int* rl, const int* ofs, const int* cnt){                     \
  gemm_core<BF32,EXPERT,GATHER,OUT,BIAS,PAIRB,ABLK>(A,B0a,B0b,B1a,B1b,bias,C,      \
      M,N,K,lda,az,bz,bshift,biasz,nsplitB,zdiv,cso,csi,ldc,alpha,ks,cspo,rl,ofs,cnt); }

GEMM_K(k_qkv,  true ,true ,false,1,true ,false,false)
GEMM_K(k_proj, true ,true ,false,0,true ,false,false)
GEMM_K(k_gup,  true ,true ,true ,3,false,true ,false)
GEMM_K(k_down, true ,true ,false,1,false,false,true )
GEMM_K(k_sgup, true ,true ,false,3,false,true ,false)
GEMM_K(k_sdown,true ,true ,false,0,false,false,true )

// ------------------------------------------------------------------
// Flash attention (verified round 18): block = 64 q-rows x 1 head.
// ------------------------------------------------------------------
__global__ __launch_bounds__(256) void k_flash(
    const bf16* __restrict__ Q, const bf16* __restrict__ Kb,
    const bf16* __restrict__ Vt, bf16* __restrict__ O)
{
  __shared__ __align__(16) bf16 plds[4][16*64];
  const int bh = blockIdx.y;
  const int b = bh / 12, hh = bh % 12;
  const int tid = threadIdx.x;
  const int wid = tid >> 6, lane = tid & 63;
  const int q0 = blockIdx.x * 64 + wid * 16;
  const int r = lane & 15, g = lane >> 4;
  const long qbase = (long)bh * 1280 * 64;
  const long vbase = (long)bh * 64 * 1280;
  bf16* pw = plds[wid];

  s16x8 qa0 = *(const s16x8*)(Q + qbase + (long)(q0 + r) * 64 + g*8);
  s16x8 qa1 = *(const s16x8*)(Q + qbase + (long)(q0 + r) * 64 + 32 + g*8);

  f32x4 oacc[4] = {};
  float m_[4] = {-1e30f,-1e30f,-1e30f,-1e30f};
  float l_[4] = {0.f,0.f,0.f,0.f};

  for (int kt = 0; kt < 20; kt++){
    const int kv0 = kt * 64;
    f32x4 sf[4];
    #pragma unroll
    for (int nf = 0; nf < 4; nf++){
      const bf16* kr = Kb + qbase + (long)(kv0 + nf*16 + r) * 64;
      s16x8 kb0 = *(const s16x8*)(kr + g*8);
      s16x8 kb1 = *(const s16x8*)(kr + 32 + g*8);
      f32x4 s = {};
      s = __builtin_amdgcn_mfma_f32_16x16x32_bf16(qa0, kb0, s, 0, 0, 0);
      s = __builtin_amdgcn_mfma_f32_16x16x32_bf16(qa1, kb1, s, 0, 0, 0);
      #pragma unroll
      for (int i = 0; i < 4; i++) s[i] *= 0.125f;
      sf[nf] = s;
    }
    float pm[4];
    #pragma unroll
    for (int i = 0; i < 4; i++)
      pm[i] = fmaxf(fmaxf(sf[0][i], sf[1][i]), fmaxf(sf[2][i], sf[3][i]));
    #pragma unroll
    for (int o = 1; o <= 8; o <<= 1)
      #pragma unroll
      for (int i = 0; i < 4; i++) pm[i] = fmaxf(pm[i], __shfl_xor(pm[i], o));
    float mn[4], al[4];
    #pragma unroll
    for (int i = 0; i < 4; i++){
      mn[i] = fmaxf(m_[i], pm[i]);
      al[i] = __expf(m_[i] - mn[i]);
    }
    float rs_[4] = {0.f,0.f,0.f,0.f};
    #pragma unroll
    for (int nf = 0; nf < 4; nf++)
      #pragma unroll
      for (int i = 0; i < 4; i++){
        float p = __expf(sf[nf][i] - mn[i]);
        sf[nf][i] = p;
        rs_[i] += p;
      }
    #pragma unroll
    for (int o = 1; o <= 8; o <<= 1)
      #pragma unroll
      for (int i = 0; i < 4; i++) rs_[i] += __shfl_xor(rs_[i], o);
    #pragma unroll
    for (int i = 0; i < 4; i++){
      l_[i] = l_[i] * al[i] + rs_[i];
      m_[i] = mn[i];
    }
    #pragma unroll
    for (int nf = 0; nf < 4; nf++)
      #pragma unroll
      for (int i = 0; i < 4; i++) oacc[nf][i] *= al[i];
    #pragma unroll
    for (int nf = 0; nf < 4; nf++)
      #pragma unroll
      for (int i = 0; i < 4; i++)
        pw[swz16(g*4 + i, nf*16 + r)] = f2bf(sf[nf][i]);
    s16x8 pa0 = *(const s16x8*)(pw + swz16(r, g*8));
    s16x8 pa1 = *(const s16x8*)(pw + swz16(r, 32 + g*8));
    #pragma unroll
    for (int nf = 0; nf < 4; nf++){
      const bf16* vr = Vt + vbase + (long)(nf*16 + r) * 1280 + kv0;
      s16x8 vb0 = *(const s16x8*)(vr + g*8);
      s16x8 vb1 = *(const s16x8*)(vr + 32 + g*8);
      oacc[nf] = __builtin_amdgcn_mfma_f32_16x16x32_bf16(pa0, vb0, oacc[nf], 0, 0, 0);
      oacc[nf] = __builtin_amdgcn_mfma_f32_16x16x32_bf16(pa1, vb1, oacc[nf], 0, 0, 0);
    }
  }
  #pragma unroll
  for (int i = 0; i < 4; i++){
    float inv = 1.f / l_[i];
    int row = q0 + g*4 + i;
    #pragma unroll
    for (int nf = 0; nf < 4; nf++)
      O[((long)b*1280 + row)*768 + hh*64 + nf*16 + r] = f2bf(oacc[nf][i] * inv);
  }
}

// ---- init: zero counts, tables, bias concat copies (replaces 4 memcpys) ----
__global__ __launch_bounds__(256) void init_kernel(int* cnt16, int* tabs,
    const float* __restrict__ iqkvb, const float* __restrict__ tqkvb,
    const float* __restrict__ tpb, const float* __restrict__ ipb,
    float* __restrict__ qb_ws, float* __restrict__ pb_ws){
  int i = blockIdx.x * 256 + threadIdx.x;
  if (i < 16) cnt16[i] = 0;
  if (i == 0){
    tabs[0]=2048; tabs[1]=512; tabs[2]=0; tabs[3]=2048;          // qkv cnt/ofs
    tabs[4]=256; tabs[5]=256; tabs[6]=1024; tabs[7]=1024;        // proj cnt
    tabs[8]=0; tabs[9]=1280; tabs[10]=256; tabs[11]=1536;        // proj ofs
    tabs[12]=2048; tabs[13]=512; tabs[14]=0; tabs[15]=2048;      // shared cnt/ofs
  }
  if (i < 2304)       qb_ws[i] = iqkvb[i];
  else if (i < 4608)  qb_ws[i] = tqkvb[i - 2304];
  else if (i < 5376)  pb_ws[i - 4608] = tpb[i - 4608];
  else if (i < 6144)  pb_ws[i - 4608] = ipb[i - 5376];
}

__global__ void tables_kernel(const int* cnt16, int* ofs16, int* cur16){
  if (threadIdx.x == 0){
    int o = 0;
    for (int e = 0; e < 8; e++){ ofs16[e] = o; o += cnt16[e]; cur16[e] = 0; }
    o = 4096;
    for (int e = 8; e < 16; e++){ ofs16[e] = o; o += cnt16[e]; cur16[e] = 0; }
  }
}

// ---- modulation GEMV (img+txt merged: grid.y 0,1=img b, 2,3=txt b) ----
__global__ __launch_bounds__(256) void mod_kernel(const float* __restrict__ vec,
    const float* __restrict__ wi, const float* __restrict__ bi,
    const float* __restrict__ wt, const float* __restrict__ bt,
    float* __restrict__ mi, float* __restrict__ mt){
  int yy = blockIdx.y;
  int bb = yy & 1;
  bool txt = yy >= 2;
  const float* w = txt ? wt : wi;
  const float* b = txt ? bt : bi;
  float* out = txt ? mt : mi;
  __shared__ float sv[768];
  int tid = threadIdx.x;
  for (int i = tid; i < 768; i += 256){ float v = vec[bb*768 + i]; sv[i] = v/(1.f+expf(-v)); }
  __syncthreads();
  int w4 = tid >> 6, lane = tid & 63;
  int j0 = blockIdx.x * 8 + w4 * 2;
  for (int jj = 0; jj < 2; jj++){
    int j = j0 + jj;
    const float* wr = w + (long)j * 768;
    float p = 0.f;
    #pragma unroll
    for (int i = 0; i < 12; i++) p += sv[lane + 64*i] * wr[lane + 64*i];
    for (int o = 32; o; o >>= 1) p += __shfl_xor(p, o);
    if (lane == 0) out[bb*4608 + j] = p + b[j];
  }
}

// ---- y = (1+c)*LN(x) + s  (img+txt merged, t global in [0,2560)) ----
__global__ __launch_bounds__(256) void ln_mod_kernel(const float* __restrict__ xi,
    const float* __restrict__ xt, const float* __restrict__ modi,
    const float* __restrict__ modt, bf16* __restrict__ y){
  int t = blockIdx.x;
  bool txt = t >= 2048;
  int tl = txt ? t - 2048 : t;
  int L = txt ? 256 : 1024;
  const float* xr = (txt ? xt : xi) + (long)tl * 768;
  const float* mb = (txt ? modt : modi) + (long)(tl / L) * 4608;
  __shared__ float red[256];
  int tid = threadIdx.x;
  float v[3]; float s = 0.f;
  #pragma unroll
  for (int i = 0; i < 3; i++){ v[i] = xr[tid + 256*i]; s += v[i]; }
  red[tid] = s; __syncthreads();
  for (int o = 128; o; o >>= 1){ if (tid < o) red[tid] += red[tid+o]; __syncthreads(); }
  float mean = red[0] * (1.f/768.f); __syncthreads();
  float s2 = 0.f;
  #pragma unroll
  for (int i = 0; i < 3; i++){ float d = v[i]-mean; s2 += d*d; }
  red[tid] = s2; __syncthreads();
  for (int o = 128; o; o >>= 1){ if (tid < o) red[tid] += red[tid+o]; __syncthreads(); }
  float rs = rsqrtf(red[0] * (1.f/768.f) + 1e-6f);
  #pragma unroll
  for (int i = 0; i < 3; i++){
    int d = tid + 256*i;
    y[(long)t*768 + d] = f2bf((1.f + mb[768+d]) * ((v[i]-mean)*rs) + mb[d]);
  }
}

// ---- h = x + g1*(pjA+pjB) ; y = (1+c2)*LN(h) + s2  (img+txt merged) ----
__global__ __launch_bounds__(256) void resid_ln_mod_kernel(const float* __restrict__ xi,
    const float* __restrict__ xt, const float* __restrict__ pj,
    const float* __restrict__ modi, const float* __restrict__ modt,
    float* __restrict__ hi, float* __restrict__ ht,
    bf16* __restrict__ y, float* __restrict__ yf){
  int t = blockIdx.x;
  bool txt = t >= 2048;
  int tl = txt ? t - 2048 : t;
  int L = txt ? 256 : 1024;
  int b = tl / L;
  int pjoff = txt ? 0 : 256;
  const float* mb = (txt ? modt : modi) + (long)b * 4608;
  const float* xr = (txt ? xt : xi) + (long)tl * 768;
  float* h = txt ? ht : hi;
  long pr = (long)(pjoff + b*1280 + (tl % L)) * 768;
  const long pjspo = (long)2560*768;
  __shared__ float red[256];
  int tid = threadIdx.x;
  float v[3]; float s = 0.f;
  #pragma unroll
  for (int i = 0; i < 3; i++){
    int d = tid + 256*i;
    float pv = pj[pr + d] + pj[pjspo + pr + d];
    float hv = xr[d] + mb[2*768 + d] * pv;
    h[(long)tl*768 + d] = hv;
    v[i] = hv; s += hv;
  }
  red[tid] = s; __syncthreads();
  for (int o = 128; o; o >>= 1){ if (tid < o) red[tid] += red[tid+o]; __syncthreads(); }
  float mean = red[0] * (1.f/768.f); __syncthreads();
  float s2 = 0.f;
  #pragma unroll
  for (int i = 0; i < 3; i++){ float d = v[i]-mean; s2 += d*d; }
  red[tid] = s2; __syncthreads();
  for (int o = 128; o; o >>= 1){ if (tid < o) red[tid] += red[tid+o]; __syncthreads(); }
  float rs = rsqrtf(red[0] * (1.f/768.f) + 1e-6f);
  #pragma unroll
  for (int i = 0; i < 3; i++){
    int d = tid + 256*i;
    float val = (1.f + mb[4*768+d]) * ((v[i]-mean)*rs) + mb[3*768+d];
    y[(long)t*768 + d] = f2bf(val);
    yf[(long)t*768 + d] = val;
  }
}

// ---- qkv rows -> RMS-normed Q,K + transposed V (img+txt merged: x<16 img) ----
__global__ __launch_bounds__(256) void qkv_scatter_kernel(const bf16* __restrict__ qrc,
    const float* __restrict__ iqs, const float* __restrict__ iks,
    const float* __restrict__ tqs, const float* __restrict__ tks,
    bf16* __restrict__ Q, bf16* __restrict__ Kb, bf16* __restrict__ Vt){
  __shared__ float vt[64][65];
  int bx = blockIdx.x;
  bool txt = bx >= 16;
  const bf16* qkv = txt ? qrc + (long)2048*2304 : qrc;
  const float* qs = txt ? tqs : iqs;
  const float* ks = txt ? tks : iks;
  int L = txt ? 256 : 1024;
  int seqoff = txt ? 0 : 256;
  int st = (txt ? bx - 16 : bx) * 64;
  int bh = blockIdx.y;
  int b = bh / 12, hh = bh % 12;
  int w = threadIdx.x >> 6, lane = threadIdx.x & 63;
  float qsc = qs[lane], ksc = ks[lane];
  long qkvbase = (long)b * L * 2304;
  long outbase = (long)bh * 1280 * 64;
  #pragma unroll 4
  for (int i = 0; i < 16; i++){
    int r = w*16 + i;
    int t = st + r;
    const bf16* row = qkv + qkvbase + (long)t * 2304;
    float q = bf2f(row[hh*64 + lane]);
    float k = bf2f(row[768 + hh*64 + lane]);
    float v = bf2f(row[1536 + hh*64 + lane]);
    float q2 = q*q, k2 = k*k;
    for (int o = 32; o; o >>= 1){ q2 += __shfl_xor(q2, o); k2 += __shfl_xor(k2, o); }
    q = q * rsqrtf(q2*(1.f/64.f) + 1e-6f) * qsc;
    k = k * rsqrtf(k2*(1.f/64.f) + 1e-6f) * ksc;
    int seq = seqoff + t;
    Q [outbase + (long)seq*64 + lane] = f2bf(q);
    Kb[outbase + (long)seq*64 + lane] = f2bf(k);
    vt[r][lane] = v;
  }
  __syncthreads();
  #pragma unroll 4
  for (int i = 0; i < 16; i++){
    int d = w*16 + i;
    Vt[outbase + (long)d*1280 + seqoff + st + lane] = f2bf(vt[lane][d]);
  }
}

// ---- router (img+txt merged: t global in [0,2560)) ----
__global__ __launch_bounds__(256) void router_kernel(const float* __restrict__ x2,
    const float* __restrict__ gwi, const float* __restrict__ gwt,
    float* __restrict__ tkwi, float* __restrict__ tkwt,
    int* __restrict__ tkii, int* __restrict__ tkit, int* __restrict__ cnt16){
  int t = blockIdx.x * 4 + (threadIdx.x >> 6);
  int lane = threadIdx.x & 63;
  if (t >= 2560) return;
  bool txt = t >= 2048;
  int tl = txt ? t - 2048 : t;
  const float* gw = txt ? gwt : gwi;
  float* tkw = txt ? tkwt : tkwi;
  int* tki = txt ? tkit : tkii;
  int* counts = cnt16 + (txt ? 8 : 0);
  const float* xr = x2 + (long)t * 768;
  float xs[12];
  #pragma unroll
  for (int i = 0; i < 12; i++) xs[i] = xr[lane + 64*i];
  float sc[8];
  #pragma unroll
  for (int e = 0; e < 8; e++){
    const float* gr = gw + e * 768;
    float p = 0.f;
    #pragma unroll
    for (int i = 0; i < 12; i++) p += xs[i] * gr[lane + 64*i];
    for (int o = 32; o; o >>= 1) p += __shfl_xor(p, o);
    sc[e] = p;
  }
  if (lane == 0){
    float m = sc[0];
    for (int e = 1; e < 8; e++) m = fmaxf(m, sc[e]);
    float s = 0.f;
    for (int e = 0; e < 8; e++){ sc[e] = expf(sc[e] - m); s += sc[e]; }
    float inv = 1.f / s;
    for (int e = 0; e < 8; e++) sc[e] *= inv;
    int i0 = 0;
    for (int e = 1; e < 8; e++) if (sc[e] > sc[i0]) i0 = e;
    int i1 = -1;
    for (int e = 0; e < 8; e++){ if (e == i0) continue; if (i1 < 0 || sc[e] > sc[i1]) i1 = e; }
    tkw[tl*2] = sc[i0]; tkw[tl*2+1] = sc[i1];
    tki[tl*2] = i0;     tki[tl*2+1] = i1;
    atomicAdd(&counts[i0], 1); atomicAdd(&counts[i1], 1);
  }
}

// ---- scatter (img+txt merged: idx<4096 img, else txt) ----
__global__ __launch_bounds__(256) void scatter_kernel(const int* __restrict__ tkii,
    const int* __restrict__ tkit, const int* __restrict__ ofs16, int* __restrict__ cur16,
    int* __restrict__ rows16, int* __restrict__ tposi, int* __restrict__ tpost){
  int idx = blockIdx.x * 256 + threadIdx.x;
  bool txt = idx >= 4096;
  int li = txt ? idx - 4096 : idx;
  const int* tki = txt ? tkit : tkii;
  int* tpos = txt ? tpost : tposi;
  int tabofs = txt ? 8 : 0;
  int rowadd = txt ? 2048 : 0;
  int t = li >> 1;
  int e = tki[li];
  int pos = atomicAdd(&cur16[tabofs + e], 1);
  int g = ofs16[tabofs + e] + pos;
  rows16[g] = rowadd + t;
  tpos[li] = g;
}

// ---- combine (img+txt merged) ----
__global__ __launch_bounds__(256) void combine_kernel(const float* __restrict__ hi,
    const float* __restrict__ ht, const float* __restrict__ modi,
    const float* __restrict__ modt, const float* __restrict__ tkwi,
    const float* __restrict__ tkwt, const int* __restrict__ tposi,
    const int* __restrict__ tpost, const bf16* __restrict__ ye,
    const float* __restrict__ ys, float* __restrict__ outi, float* __restrict__ outt){
  int t = blockIdx.x;
  bool txt = t >= 2048;
  int tl = txt ? t - 2048 : t;
  int L = txt ? 256 : 1024;
  int b = tl / L;
  const float* h = txt ? ht : hi;
  const float* g2 = (txt ? modt : modi) + (long)b * 4608 + 5*768;
  const float* tkw = txt ? tkwt : tkwi;
  const int* tpos = txt ? tpost : tposi;
  float* out = txt ? outt : outi;
  const long espo = (long)5120*768, sspo = (long)2560*768;
  float w0 = tkw[tl*2], w1 = tkw[tl*2+1];
  long p0 = (long)tpos[tl*2] * 768, p1 = (long)tpos[tl*2+1] * 768;
  for (int d = threadIdx.x; d < 768; d += 256){
    float e0 = 0.f, e1 = 0.f, sv = 0.f;
    #pragma unroll
    for (int sp = 0; sp < 8; sp++){
      e0 += bf2f(ye[sp*espo + p0 + d]);
      e1 += bf2f(ye[sp*espo + p1 + d]);
    }
    #pragma unroll
    for (int sp = 0; sp < 2; sp++) sv += ys[sp*sspo + (long)t*768 + d];
    out[(long)tl*768 + d] = h[(long)tl*768 + d] + g2[d] * (w0*e0 + w1*e1 + sv);
  }
}

// =================================================================================
extern "C" void kernel_launch(void* const* d_in, const int* in_sizes, int n_in,
                              void* d_out, int out_size, void* d_ws, size_t ws_size,
                              hipStream_t stream){
  (void)in_sizes; (void)n_in; (void)out_size; (void)ws_size;
  const float* fin[33];
  for (int i = 0; i < 33; i++) fin[i] = (const float*)d_in[i];
  float* out_img = (float*)d_out;
  float* out_txt = (float*)d_out + (long)2*1024*768;

  char* ws = (char*)d_ws;
  size_t off = 0;
  auto alloc = [&](size_t n)->char*{
    off = (off + 255) & ~(size_t)255;
    char* p = ws + off; off += n; return p;
  };

  // ---- persistent ----
  float* mod_i=(float*)alloc(2*4608*4);
  float* mod_t=(float*)alloc(2*4608*4);
  float* h_i  =(float*)alloc((size_t)2048*768*4);
  float* h_t  =(float*)alloc((size_t)512*768*4);
  bf16*  x2c  =(bf16*) alloc((size_t)2560*768*2);
  float* x2fc =(float*)alloc((size_t)2560*768*4);
  float* tkw_i=(float*)alloc(2048*2*4);
  int*   tki_i=(int*)  alloc(2048*2*4);
  float* tkw_t=(float*)alloc(512*2*4);
  int*   tki_t=(int*)  alloc(512*2*4);
  int* cnt16=(int*)alloc(16*4);
  int* ofs16=(int*)alloc(16*4);
  int* cur16=(int*)alloc(16*4);
  int* rows16=(int*)alloc(5120*4);
  int* tpos_i=(int*)alloc(4096*4);
  int* tpos_t=(int*)alloc(1024*4);
  int* tabs=(int*)alloc(64*4);
  float* qb_ws=(float*)alloc(2*2304*4);
  float* pb_ws=(float*)alloc(2*768*4);

  size_t arena = (off + 255) & ~(size_t)255;
  // ---- phase A ----
  off = arena;
  bf16* Qb=(bf16*)alloc((size_t)24*1280*64*2);
  bf16* Kb=(bf16*)alloc((size_t)24*1280*64*2);
  bf16* Vt=(bf16*)alloc((size_t)24*1280*64*2);
  bf16* O =(bf16*)alloc((size_t)2*1280*768*2);
  float* pjc=(float*)alloc((size_t)2*2560*768*4);
  bf16* xmc=(bf16*)alloc((size_t)2560*768*2);
  bf16* qrc=(bf16*)alloc((size_t)2560*2304*2);
  // ---- phase B (overlays phase A) ----
  off = arena;
  bf16*  h1 =(bf16*) alloc((size_t)48*5120*64*2);    // kblk-major silu(g)*u
  bf16*  ye =(bf16*) alloc((size_t)8*5120*768*2);    // 8 k-split partials (bf16)
  bf16*  h1s=(bf16*) alloc((size_t)24*2560*64*2);    // kblk-major shared
  float* ys =(float*)alloc((size_t)2*2560*768*4);

  init_kernel<<<24, 256, 0, stream>>>(cnt16, tabs, fin[8], fin[12], fin[14], fin[10],
      qb_ws, pb_ws);
  mod_kernel<<<dim3(576,4), 256, 0, stream>>>(fin[2], fin[3], fin[4], fin[5], fin[6],
      mod_i, mod_t);
  ln_mod_kernel<<<2560, 256, 0, stream>>>(fin[0], fin[1], mod_i, mod_t, xmc);

  // QKV: z=2 (img table 0, txt table 1); f32 B
  k_qkv<<<dim3(18,16,2), 256, 0, stream>>>(xmc, fin[7], fin[7], fin[11], fin[11],
      qb_ws, qrc, 0, 2304, 768, 768, 0, 0, 0, 2304, 2304,
      1, 0, 0, 2304, 1.f, 1, 0, nullptr, tabs+2, tabs+0);
  qkv_scatter_kernel<<<dim3(20,24), 256, 0, stream>>>(qrc, fin[15], fin[16],
      fin[17], fin[18], Qb, Kb, Vt);

  // flash attention
  k_flash<<<dim3(20,24), 256, 0, stream>>>(Qb, Kb, Vt, O);

  // proj: z=4 tables, bidx=z>>1, ks=2 (f32 B)
  k_proj<<<dim3(6,8,8), 256, 0, stream>>>(O, fin[13], fin[13], fin[9], fin[9],
      pb_ws, pjc, 0, 768, 768, 768, 0, 0, 1, 768, 768,
      1, 0, 0, 768, 1.f, 2, (long)2560*768, nullptr, tabs+8, tabs+4);
  resid_ln_mod_kernel<<<2560, 256, 0, stream>>>(fin[0], fin[1], pjc, mod_i, mod_t,
      h_i, h_t, x2c, x2fc);

  router_kernel<<<640, 256, 0, stream>>>(x2fc, fin[19], fin[26],
      tkw_i, tkw_t, tki_i, tki_t, cnt16);
  tables_kernel<<<1, 1, 0, stream>>>(cnt16, ofs16, cur16);
  scatter_kernel<<<20, 256, 0, stream>>>(tki_i, tki_t, ofs16, cur16,
      rows16, tpos_i, tpos_t);

  // expert gate/up pair-interleaved -> kblk-major h1 (per-m-tile grid, early exit)
  k_gup<<<dim3(48,16,16), 256, 0, stream>>>(x2c, fin[20], fin[21], fin[27], fin[28],
      nullptr, h1, 0, 6144, 768, 768, 0, (long)3072*768, 3, 0, 0,
      1, 0, 0, 5120, 1.f, 1, 0, rows16, ofs16, cnt16);
  // expert down: A = h1 kblk-major (lda=5120), K=3072, ks=8 (per-m-tile grid)
  k_down<<<dim3(6,16,128), 256, 0, stream>>>(h1, fin[22], fin[22], fin[29], fin[29],
      nullptr, ye, 0, 768, 3072, 5120, 0, (long)768*3072, 3, 0, 768,
      1, 0, 0, 768, 1.f, 8, (long)5120*768, nullptr, ofs16, cnt16);
  // shared gate/up pair-interleaved -> kblk-major h1s (Mtot = 2560)
  k_sgup<<<dim3(24,16,2), 256, 0, stream>>>(x2c, fin[23], fin[24], fin[30], fin[31],
      nullptr, h1s, 0, 3072, 768, 768, 0, 0, 0, 0, 0,
      1, 0, 0, 2560, 1.f, 1, 0, nullptr, tabs+14, tabs+12);
  // shared down: A = h1s kblk-major (lda = 2560), K=1536, ks=2
  k_sdown<<<dim3(6,16,4), 256, 0, stream>>>(h1s, fin[25], fin[25], fin[32], fin[32],
      nullptr, ys, 0, 768, 1536, 2560, 0, 0, 0, 0, 768,
      1, 0, 0, 768, 1.f, 2, (long)2560*768, nullptr, tabs+14, tabs+12);

  combine_kernel<<<2560, 256, 0, stream>>>(h_i, h_t, mod_i, mod_t,
      tkw_i, tkw_t, tpos_i, tpos_t, ye, ys, out_img, out_txt);
}